// Round 1
// baseline (1093.222 us; speedup 1.0000x reference)
//
#include <hip/hip_runtime.h>
#include <cstdint>

#define L_SEQ 32400
#define HWSZ  32400
#define NCH   127
#define DPROJ 524
#define NH    4
#define HD    64
#define NST   4

__device__ __forceinline__ float silu_f(float v) { return v / (1.f + __expf(-v)); }
__device__ __forceinline__ float softplus_f(float v) { return v > 20.f ? v : log1pf(__expf(v)); }

// ---------------------------------------------------------------------------
// Tiled f32 GEMM: out[l, n] = sum_k A(l,k) * W[n*K + k]
// If mor != nullptr:  A(l,k) = xsrc[k*HWSZ + mor[l]]   (gathered input projection)
// else:               A(l,k) = A[l*K + k]
// 64x64 tile, BK=16, 256 threads, 4x4 per thread.
// ---------------------------------------------------------------------------
__launch_bounds__(256)
__global__ void gemm_k(const float* __restrict__ A, const float* __restrict__ W,
                       float* __restrict__ out, const int* __restrict__ mor,
                       const float* __restrict__ xsrc,
                       int M, int N, int K, int ldo)
{
    __shared__ float As[16][65];
    __shared__ float Bs[16][65];
    const int l0 = blockIdx.x * 64, n0 = blockIdx.y * 64;
    const int tid = threadIdx.x;
    const int tx = tid & 15, ty = tid >> 4;
    float acc[4][4] = {};

    const int am = tid & 63, ak = tid >> 6;      // gather-mode A mapping
    int gA = -1;
    if (mor) { int l = l0 + am; gA = (l < M) ? mor[l] : -1; }
    const int lm = tid >> 2, lk4 = (tid & 3) * 4; // linear-mode mapping

    for (int kc = 0; kc < K; kc += 16) {
        if (mor) {
#pragma unroll
            for (int i = 0; i < 4; ++i) {
                int kk = ak + i * 4;
                As[kk][am] = (gA >= 0) ? xsrc[(size_t)(kc + kk) * HWSZ + gA] : 0.f;
            }
        } else {
            int l = l0 + lm;
            float4 v = make_float4(0.f, 0.f, 0.f, 0.f);
            if (l < M) v = *(const float4*)(A + (size_t)l * K + kc + lk4);
            As[lk4 + 0][lm] = v.x; As[lk4 + 1][lm] = v.y;
            As[lk4 + 2][lm] = v.z; As[lk4 + 3][lm] = v.w;
        }
        {
            int gn = n0 + lm;
            float4 v = make_float4(0.f, 0.f, 0.f, 0.f);
            if (gn < N) v = *(const float4*)(W + (size_t)gn * K + kc + lk4);
            Bs[lk4 + 0][lm] = v.x; Bs[lk4 + 1][lm] = v.y;
            Bs[lk4 + 2][lm] = v.z; Bs[lk4 + 3][lm] = v.w;
        }
        __syncthreads();
#pragma unroll
        for (int kk = 0; kk < 16; ++kk) {
            float a[4], b[4];
#pragma unroll
            for (int i = 0; i < 4; ++i) a[i] = As[kk][ty * 4 + i];
#pragma unroll
            for (int j = 0; j < 4; ++j) b[j] = Bs[kk][tx * 4 + j];
#pragma unroll
            for (int i = 0; i < 4; ++i)
#pragma unroll
                for (int j = 0; j < 4; ++j) acc[i][j] += a[i] * b[j];
        }
        __syncthreads();
    }
#pragma unroll
    for (int i = 0; i < 4; ++i) {
        int l = l0 + ty * 4 + i;
        if (l >= M) continue;
        int n = n0 + tx * 4;
        if (n < N) {  // N is a multiple of 4 in all uses -> full float4
            float4 v = make_float4(acc[i][0], acc[i][1], acc[i][2], acc[i][3]);
            *(float4*)(out + (size_t)l * ldo + n) = v;
        }
    }
}

// ---------------------------------------------------------------------------
// Per-chunk prep: dt = softplus(dt_raw + bias), B/C = silu, a = dt * (-exp(Alog)),
// inclusive cumsum of a within chunk (acs), chunk totals (csum).
// grid = NCH blocks of 256 threads (one chunk each).
// ---------------------------------------------------------------------------
__launch_bounds__(256)
__global__ void prep_k(const float* __restrict__ zx, const float* __restrict__ dt_bias,
                       const float* __restrict__ A_log, float* __restrict__ dtb,
                       float* __restrict__ Bb, float* __restrict__ Cb,
                       float* __restrict__ acsb, float* __restrict__ csum)
{
    const int c = blockIdx.x;
    const int l = threadIdx.x;
    const int gl = c * 256 + l;
    const bool valid = gl < L_SEQ;
    float a[NH] = {0.f, 0.f, 0.f, 0.f};
    if (valid) {
        const float* row = zx + (size_t)gl * DPROJ;
        float4 bv = *(const float4*)(row + 512);
        float4 cv = *(const float4*)(row + 516);
        float4 dv = *(const float4*)(row + 520);
        Bb[(size_t)gl * 4 + 0] = silu_f(bv.x);
        Bb[(size_t)gl * 4 + 1] = silu_f(bv.y);
        Bb[(size_t)gl * 4 + 2] = silu_f(bv.z);
        Bb[(size_t)gl * 4 + 3] = silu_f(bv.w);
        Cb[(size_t)gl * 4 + 0] = silu_f(cv.x);
        Cb[(size_t)gl * 4 + 1] = silu_f(cv.y);
        Cb[(size_t)gl * 4 + 2] = silu_f(cv.z);
        Cb[(size_t)gl * 4 + 3] = silu_f(cv.w);
        const float* dp = (const float*)&dv;
#pragma unroll
        for (int h = 0; h < NH; ++h) {
            float dt = softplus_f(dp[h] + dt_bias[h]);
            dtb[(size_t)gl * 4 + h] = dt;
            a[h] = -__expf(A_log[h]) * dt;
        }
    }
    __shared__ float sb[256];
#pragma unroll 1
    for (int h = 0; h < NH; ++h) {
        float v = a[h];
        sb[l] = v;
        __syncthreads();
        for (int off = 1; off < 256; off <<= 1) {
            float t = (l >= off) ? sb[l - off] : 0.f;
            __syncthreads();
            v += t;
            sb[l] = v;
            __syncthreads();
        }
        if (valid) acsb[(size_t)gl * 4 + h] = v;
        if (l == 255) csum[c * 4 + h] = v;
        __syncthreads();
    }
}

// ---------------------------------------------------------------------------
// Chunk-end states: states[c,h,p,n] = sum_l B[l,n]*exp(cs-acs[l])*dt[l]*silu(x[l,h,p])
// grid = (NCH, NH), 256 threads (p = tid>>2, n = tid&3)
// ---------------------------------------------------------------------------
__launch_bounds__(256)
__global__ void states_k(const float* __restrict__ zx, const float* __restrict__ dtb,
                         const float* __restrict__ Bb, const float* __restrict__ acs,
                         const float* __restrict__ csum, float* __restrict__ states)
{
    const int c = blockIdx.x, h = blockIdx.y;
    const int p = threadIdx.x >> 2, n = threadIdx.x & 3;
    const float cs = csum[c * 4 + h];
    float acc = 0.f;
    const int lmax = (c * 256 + 256 <= L_SEQ) ? 256 : (L_SEQ - c * 256);
    for (int l = 0; l < lmax; ++l) {
        const int gl = c * 256 + l;
        float xs = silu_f(zx[(size_t)gl * DPROJ + 256 + h * HD + p]);
        acc += Bb[(size_t)gl * 4 + n] * __expf(cs - acs[(size_t)gl * 4 + h])
             * dtb[(size_t)gl * 4 + h] * xs;
    }
    states[((size_t)(c * NH + h) * HD + p) * NST + n] = acc;
}

// ---------------------------------------------------------------------------
// Sequential inter-chunk scan: prev[0]=0; prev[c+1]=exp(csum[c])*prev[c]+states[c]
// 1 block, 1024 threads: (h = tid>>8, pn = tid&255)
// ---------------------------------------------------------------------------
__global__ void chunkscan_k(const float* __restrict__ csum, const float* __restrict__ states,
                            float* __restrict__ prev)
{
    const int tid = threadIdx.x;
    const int h = tid >> 8, pn = tid & 255;
    float run = 0.f;
    for (int c = 0; c < NCH; ++c) {
        prev[(size_t)(c * NH + h) * 256 + pn] = run;
        run = run * __expf(csum[c * 4 + h]) + states[(size_t)(c * NH + h) * 256 + pn];
    }
}

// ---------------------------------------------------------------------------
// Per-chunk output: Y[l,p] = sum_{s<=l} (C_l.B_s) exp(acs_l-acs_s) dt_s xs[s,p]
//                   + exp(acs_l) * (C_l . prev[p,:])  + D*xs[l,p], then * silu(z)
// grid = (NCH, NH, 2) : blockIdx.z = p-half (32 cols). 256 threads = rows.
// Scatter rows to cat[morton[gl], catOff + h*64 + ph*32 + p].
// ---------------------------------------------------------------------------
__launch_bounds__(256)
__global__ void ychunk_k(const float* __restrict__ zx, const float* __restrict__ dtb,
                         const float* __restrict__ Bb, const float* __restrict__ Cb,
                         const float* __restrict__ acs, const float* __restrict__ prev,
                         const float* __restrict__ Dv, const int* __restrict__ mor,
                         float* __restrict__ cat, int catOff)
{
    __shared__ float Xs[256][36];   // padded: 36 = 32 + 4 to break bank alignment
    __shared__ float4 Bs[256];
    __shared__ float4 Cs[256];
    __shared__ float as_s[256];
    __shared__ float dt_s[256];
    __shared__ float4 pv_s[32];
    const int c = blockIdx.x, h = blockIdx.y, ph = blockIdx.z;
    const int l = threadIdx.x;
    const int gl = c * 256 + l;
    const bool valid = gl < L_SEQ;
    if (valid) {
        const float4* xrow = (const float4*)(zx + (size_t)gl * DPROJ + 256 + h * HD + ph * 32);
#pragma unroll
        for (int q = 0; q < 8; ++q) {
            float4 v = xrow[q];
            Xs[l][q * 4 + 0] = silu_f(v.x);
            Xs[l][q * 4 + 1] = silu_f(v.y);
            Xs[l][q * 4 + 2] = silu_f(v.z);
            Xs[l][q * 4 + 3] = silu_f(v.w);
        }
        Bs[l] = *(const float4*)(Bb + (size_t)gl * 4);
        Cs[l] = *(const float4*)(Cb + (size_t)gl * 4);
        as_s[l] = acs[(size_t)gl * 4 + h];
        dt_s[l] = dtb[(size_t)gl * 4 + h];
    } else {
#pragma unroll
        for (int q = 0; q < 32; ++q) Xs[l][q] = 0.f;
        Bs[l] = make_float4(0.f, 0.f, 0.f, 0.f);
        Cs[l] = make_float4(0.f, 0.f, 0.f, 0.f);
        as_s[l] = 0.f; dt_s[l] = 0.f;
    }
    if (l < 32)
        pv_s[l] = *(const float4*)(prev + ((size_t)(c * NH + h) * HD + ph * 32 + l) * 4);
    __syncthreads();

    float y[32];
#pragma unroll
    for (int p = 0; p < 32; ++p) y[p] = 0.f;
    const float4 cl = Cs[l];
    const float al = as_s[l];
    for (int s = 0; s < 256; ++s) {
        float4 bs = Bs[s];
        float w = cl.x * bs.x + cl.y * bs.y + cl.z * bs.z + cl.w * bs.w;
        w = (s <= l) ? w * __expf(al - as_s[s]) * dt_s[s] : 0.f;
        const float4* xr = (const float4*)(&Xs[s][0]);
#pragma unroll
        for (int q = 0; q < 8; ++q) {
            float4 xv = xr[q];
            y[q * 4 + 0] += w * xv.x;
            y[q * 4 + 1] += w * xv.y;
            y[q * 4 + 2] += w * xv.z;
            y[q * 4 + 3] += w * xv.w;
        }
    }
    if (valid) {
        const float eal = __expf(al);
        const float dco = Dv[h];
#pragma unroll
        for (int p = 0; p < 32; ++p) {
            float4 pp = pv_s[p];
            y[p] += eal * (cl.x * pp.x + cl.y * pp.y + cl.z * pp.z + cl.w * pp.w)
                  + dco * Xs[l][p];
        }
        const int pos = mor[gl];
        float* orow = cat + (size_t)pos * 512 + catOff + h * HD + ph * 32;
        const float4* zrow = (const float4*)(zx + (size_t)gl * DPROJ + h * HD + ph * 32);
#pragma unroll
        for (int q = 0; q < 8; ++q) {
            float4 zv = zrow[q];
            float4 o;
            o.x = y[q * 4 + 0] * silu_f(zv.x);
            o.y = y[q * 4 + 1] * silu_f(zv.y);
            o.z = y[q * 4 + 2] * silu_f(zv.z);
            o.w = y[q * 4 + 3] * silu_f(zv.w);
            *(float4*)(orow + q * 4) = o;
        }
    }
}

// ---------------------------------------------------------------------------
// LayerNorm over channel dim (256). One block per row.
// ---------------------------------------------------------------------------
__launch_bounds__(256)
__global__ void ln_k(const float* __restrict__ pin, const float* __restrict__ g,
                     const float* __restrict__ b, float* __restrict__ pout)
{
    const int l = blockIdx.x, c = threadIdx.x;
    float v = pin[(size_t)l * 256 + c];
    float s = v, s2 = v * v;
#pragma unroll
    for (int o = 32; o > 0; o >>= 1) { s += __shfl_down(s, o); s2 += __shfl_down(s2, o); }
    __shared__ float ws0[4], ws1[4];
    if ((c & 63) == 0) { ws0[c >> 6] = s; ws1[c >> 6] = s2; }
    __syncthreads();
    float ts = ws0[0] + ws0[1] + ws0[2] + ws0[3];
    float t2 = ws1[0] + ws1[1] + ws1[2] + ws1[3];
    float mu = ts * (1.f / 256.f);
    float var = t2 * (1.f / 256.f) - mu * mu;
    float r = rsqrtf(var + 1e-6f);
    pout[(size_t)l * 256 + c] = (v - mu) * r * g[c] + b[c];
}

// ---------------------------------------------------------------------------
// Transpose (L x 256) -> (256 x L) with 64x64 LDS tiles.
// ---------------------------------------------------------------------------
__global__ void transpose_k(const float* __restrict__ pin, float* __restrict__ pout)
{
    __shared__ float t[64][65];
    const int l0 = blockIdx.x * 64, c0 = blockIdx.y * 64;
    const int tx = threadIdx.x, ty = threadIdx.y; // (64,4)
#pragma unroll
    for (int j = 0; j < 16; ++j) {
        int row = ty + j * 4;
        int l = l0 + row;
        t[row][tx] = (l < L_SEQ) ? pin[(size_t)l * 256 + c0 + tx] : 0.f;
    }
    __syncthreads();
#pragma unroll
    for (int j = 0; j < 16; ++j) {
        int crow = ty + j * 4;
        int lcol = l0 + tx;
        if (lcol < L_SEQ) pout[(size_t)(c0 + crow) * L_SEQ + lcol] = t[tx][crow];
    }
}

// ---------------------------------------------------------------------------
extern "C" void kernel_launch(void* const* d_in, const int* in_sizes, int n_in,
                              void* d_out, int out_size, void* d_ws, size_t ws_size,
                              hipStream_t stream)
{
    const float* x        = (const float*)d_in[0];
    const float* W_in[2]  = {(const float*)d_in[1], (const float*)d_in[2]};
    const float* dt_b[2]  = {(const float*)d_in[3], (const float*)d_in[4]};
    const float* A_log[2] = {(const float*)d_in[5], (const float*)d_in[6]};
    const float* Dv[2]    = {(const float*)d_in[7], (const float*)d_in[8]};
    const float* W_out    = (const float*)d_in[9];
    const float* ln_g     = (const float*)d_in[10];
    const float* ln_b     = (const float*)d_in[11];
    const int*   mor[2]   = {(const int*)d_in[12], (const int*)d_in[13]};

    float* ws = (float*)d_ws;
    size_t off = 0;
    auto alloc = [&](size_t n) { float* p = ws + off; off += (n + 63) & ~(size_t)63; return p; };
    float* zx     = alloc((size_t)L_SEQ * DPROJ);   // 67.9 MB (reused as proj out)
    float* cat    = alloc((size_t)L_SEQ * 512);     // 66.4 MB (reused as LN out)
    float* dtb    = alloc((size_t)L_SEQ * 4);
    float* Bb     = alloc((size_t)L_SEQ * 4);
    float* Cb     = alloc((size_t)L_SEQ * 4);
    float* acsb   = alloc((size_t)L_SEQ * 4);
    float* csum   = alloc((size_t)NCH * 4);
    float* states = alloc((size_t)NCH * NH * HD * NST);
    float* prev   = alloc((size_t)NCH * NH * HD * NST);
    float* proj   = zx;    // safe reuse: zx dead after both paths complete
    float* lnout  = cat;   // safe reuse: cat dead after out-proj GEMM

    for (int path = 0; path < 2; ++path) {
        gemm_k<<<dim3(507, 9), 256, 0, stream>>>(nullptr, W_in[path], zx, mor[path], x,
                                                 L_SEQ, DPROJ, 256, DPROJ);
        prep_k<<<NCH, 256, 0, stream>>>(zx, dt_b[path], A_log[path], dtb, Bb, Cb, acsb, csum);
        states_k<<<dim3(NCH, NH), 256, 0, stream>>>(zx, dtb, Bb, acsb, csum, states);
        chunkscan_k<<<1, 1024, 0, stream>>>(csum, states, prev);
        ychunk_k<<<dim3(NCH, NH, 2), 256, 0, stream>>>(zx, dtb, Bb, Cb, acsb, prev,
                                                       Dv[path], mor[path], cat, path * 256);
    }
    gemm_k<<<dim3(507, 4), 256, 0, stream>>>(cat, W_out, proj, nullptr, nullptr,
                                             L_SEQ, 256, 512, 256);
    ln_k<<<L_SEQ, 256, 0, stream>>>(proj, ln_g, ln_b, lnout);
    transpose_k<<<dim3(507, 4), dim3(64, 4), 0, stream>>>(lnout, (float*)d_out);
}

// Round 2
// 673.464 us; speedup vs baseline: 1.6233x; 1.6233x over previous
//
#include <hip/hip_runtime.h>
#include <cstdint>

#define L_SEQ 32400
#define HWSZ  32400
#define MPAD  32512
#define NCH   127
#define DPROJ 524
#define NH    4
#define HD    64
#define NST   4

typedef unsigned short u16;
typedef unsigned int   u32;
typedef __attribute__((ext_vector_type(8))) short short8;
typedef __attribute__((ext_vector_type(4))) float f32x4;

__device__ __forceinline__ float silu_f(float v) { return v / (1.f + __expf(-v)); }
__device__ __forceinline__ float softplus_f(float v) { return v > 20.f ? v : log1pf(__expf(v)); }
__device__ __forceinline__ u16 f2bf(float f) {
    u32 u = __float_as_uint(f);
    u += 0x7FFFu + ((u >> 16) & 1u);
    return (u16)(u >> 16);
}
__device__ __forceinline__ void gload16(const void* g, void* l) {
    __builtin_amdgcn_global_load_lds(
        (const __attribute__((address_space(1))) u32*)(uintptr_t)g,
        (__attribute__((address_space(3))) u32*)(u32)(uintptr_t)l,
        16, 0, 0);
}

// ---------------------------------------------------------------------------
// Gather + transpose + bf16 pack: xg[inv[pix]][c] = bf16(x[c][pix]).
// Block: 64 pixels x 256 channels. Both phases coalesced.
// ---------------------------------------------------------------------------
__launch_bounds__(256)
__global__ void gather_k(const float* __restrict__ x, const int* __restrict__ inv,
                         u16* __restrict__ xg)
{
    __shared__ u16 tile[256][66];
    const int pix0 = blockIdx.x * 64;
    const int tid = threadIdx.x;
    const int pl = tid & 63, cq = tid >> 6;
    const int pix = pix0 + pl;
    const bool pv = pix < HWSZ;
#pragma unroll 4
    for (int j = 0; j < 64; ++j) {
        int c = cq * 64 + j;
        float v = pv ? x[(size_t)c * HWSZ + pix] : 0.f;
        tile[c][pl] = f2bf(v);
    }
    __syncthreads();
    for (int i = 0; i < 64; ++i) {
        int p2 = pix0 + i;
        if (p2 < HWSZ) {
            int row = inv[p2];
            xg[(size_t)row * 256 + tid] = tile[tid][i];
        }
    }
}

__global__ void zero_k(u16* __restrict__ p, int n)
{
    int i = blockIdx.x * 256 + threadIdx.x;
    if (i < n) p[i] = 0;
}

// Convert f32 [rows][cols] -> bf16 [rowsPad][cols], pad rows zeroed.
__global__ void convpad_k(const float* __restrict__ src, u16* __restrict__ dst,
                          int rows, int cols, int rowsPad)
{
    int r = blockIdx.x;
    for (int c = threadIdx.x; c < cols; c += 256)
        dst[(size_t)r * cols + c] = (r < rows) ? f2bf(src[(size_t)r * cols + c]) : (u16)0;
}

// ---------------------------------------------------------------------------
// bf16 MFMA GEMM (gemm_bt): out[m][n] = sum_k A[m][k]*B[n][k]  (f32 out)
// A: [Mpad][K] bf16, B: [Npad][K] bf16 (both padded, no staging bounds).
// 128x128 tile, BK=64, 4 waves (2x2 of 64x64), 16x16x32 MFMA,
// global_load_lds width-16 staging (m97 structure).
// ---------------------------------------------------------------------------
__launch_bounds__(256)
__global__ void mfma_gemm_k(const u16* __restrict__ A, const u16* __restrict__ B,
                            float* __restrict__ out, int K, int Nout, int M, int ldo)
{
    __shared__ u16 As[128 * 64];
    __shared__ u16 Bs[128 * 64];
    const int r0 = blockIdx.x * 128, c0 = blockIdx.y * 128;
    const int tid = threadIdx.x;
    const int lane = tid & 63, w = tid >> 6;
    const int wr = (w >> 1) * 64, wc = (w & 1) * 64;
    f32x4 acc[4][4];
#pragma unroll
    for (int m = 0; m < 4; ++m)
#pragma unroll
        for (int n = 0; n < 4; ++n)
            acc[m][n] = (f32x4){0.f, 0.f, 0.f, 0.f};

    const int rlane = lane & 15;
    const int khalf = (lane >> 4) * 16;   // byte offset of this lane's 8 bf16 along k

    for (int k0 = 0; k0 < K; k0 += 64) {
#pragma unroll
        for (int i = 0; i < 4; ++i) {
            int chunk = i * 256 + tid;          // 1024 chunks of 16B = 16KB tile
            int row = chunk >> 3, ks = chunk & 7;
            gload16(A + ((size_t)(r0 + row) * K + k0 + ks * 8), (char*)As + chunk * 16);
            gload16(B + ((size_t)(c0 + row) * K + k0 + ks * 8), (char*)Bs + chunk * 16);
        }
        __syncthreads();
#pragma unroll
        for (int ks = 0; ks < 2; ++ks) {
            short8 a[4], b[4];
#pragma unroll
            for (int m = 0; m < 4; ++m)
                a[m] = *(const short8*)((const char*)As + (wr + m * 16 + rlane) * 128 + ks * 64 + khalf);
#pragma unroll
            for (int n = 0; n < 4; ++n)
                b[n] = *(const short8*)((const char*)Bs + (wc + n * 16 + rlane) * 128 + ks * 64 + khalf);
#pragma unroll
            for (int m = 0; m < 4; ++m)
#pragma unroll
                for (int n = 0; n < 4; ++n)
                    acc[m][n] = __builtin_amdgcn_mfma_f32_16x16x32_bf16(a[m], b[n], acc[m][n], 0, 0, 0);
        }
        __syncthreads();
    }
    const int rl = (lane >> 4) * 4, cl = lane & 15;
#pragma unroll
    for (int m = 0; m < 4; ++m) {
#pragma unroll
        for (int n = 0; n < 4; ++n) {
            int col = c0 + wc + n * 16 + cl;
            if (col >= Nout) continue;
#pragma unroll
            for (int r = 0; r < 4; ++r) {
                int row = r0 + wr + m * 16 + rl + r;
                if (row < M) out[(size_t)row * ldo + col] = acc[m][n][r];
            }
        }
    }
}

// ---------------------------------------------------------------------------
// Per-chunk prep: dt = softplus(dt_raw + bias), B/C = silu, a = dt * (-exp(Alog)),
// inclusive cumsum of a within chunk (acs), chunk totals (csum).
// ---------------------------------------------------------------------------
__launch_bounds__(256)
__global__ void prep_k(const float* __restrict__ zx, const float* __restrict__ dt_bias,
                       const float* __restrict__ A_log, float* __restrict__ dtb,
                       float* __restrict__ Bb, float* __restrict__ Cb,
                       float* __restrict__ acsb, float* __restrict__ csum)
{
    const int c = blockIdx.x;
    const int l = threadIdx.x;
    const int gl = c * 256 + l;
    const bool valid = gl < L_SEQ;
    float a[NH] = {0.f, 0.f, 0.f, 0.f};
    if (valid) {
        const float* row = zx + (size_t)gl * DPROJ;
        float4 bv = *(const float4*)(row + 512);
        float4 cv = *(const float4*)(row + 516);
        float4 dv = *(const float4*)(row + 520);
        Bb[(size_t)gl * 4 + 0] = silu_f(bv.x);
        Bb[(size_t)gl * 4 + 1] = silu_f(bv.y);
        Bb[(size_t)gl * 4 + 2] = silu_f(bv.z);
        Bb[(size_t)gl * 4 + 3] = silu_f(bv.w);
        Cb[(size_t)gl * 4 + 0] = silu_f(cv.x);
        Cb[(size_t)gl * 4 + 1] = silu_f(cv.y);
        Cb[(size_t)gl * 4 + 2] = silu_f(cv.z);
        Cb[(size_t)gl * 4 + 3] = silu_f(cv.w);
        const float* dp = (const float*)&dv;
#pragma unroll
        for (int h = 0; h < NH; ++h) {
            float dt = softplus_f(dp[h] + dt_bias[h]);
            dtb[(size_t)gl * 4 + h] = dt;
            a[h] = -__expf(A_log[h]) * dt;
        }
    }
    __shared__ float sb[256];
#pragma unroll 1
    for (int h = 0; h < NH; ++h) {
        float v = a[h];
        sb[l] = v;
        __syncthreads();
        for (int off = 1; off < 256; off <<= 1) {
            float t = (l >= off) ? sb[l - off] : 0.f;
            __syncthreads();
            v += t;
            sb[l] = v;
            __syncthreads();
        }
        if (valid) acsb[(size_t)gl * 4 + h] = v;
        if (l == 255) csum[c * 4 + h] = v;
        __syncthreads();
    }
}

// ---------------------------------------------------------------------------
// Chunk-end states.
// ---------------------------------------------------------------------------
__launch_bounds__(256)
__global__ void states_k(const float* __restrict__ zx, const float* __restrict__ dtb,
                         const float* __restrict__ Bb, const float* __restrict__ acs,
                         const float* __restrict__ csum, float* __restrict__ states)
{
    const int c = blockIdx.x, h = blockIdx.y;
    const int p = threadIdx.x >> 2, n = threadIdx.x & 3;
    const float cs = csum[c * 4 + h];
    float acc = 0.f;
    const int lmax = (c * 256 + 256 <= L_SEQ) ? 256 : (L_SEQ - c * 256);
    for (int l = 0; l < lmax; ++l) {
        const int gl = c * 256 + l;
        float xs = silu_f(zx[(size_t)gl * DPROJ + 256 + h * HD + p]);
        acc += Bb[(size_t)gl * 4 + n] * __expf(cs - acs[(size_t)gl * 4 + h])
             * dtb[(size_t)gl * 4 + h] * xs;
    }
    states[((size_t)(c * NH + h) * HD + p) * NST + n] = acc;
}

// ---------------------------------------------------------------------------
// Sequential inter-chunk scan.
// ---------------------------------------------------------------------------
__global__ void chunkscan_k(const float* __restrict__ csum, const float* __restrict__ states,
                            float* __restrict__ prev)
{
    const int tid = threadIdx.x;
    const int h = tid >> 8, pn = tid & 255;
    float run = 0.f;
    for (int c = 0; c < NCH; ++c) {
        prev[(size_t)(c * NH + h) * 256 + pn] = run;
        run = run * __expf(csum[c * 4 + h]) + states[(size_t)(c * NH + h) * 256 + pn];
    }
}

// ---------------------------------------------------------------------------
// Per-chunk output; scatters gated output rows into bf16 cat buffer.
// ---------------------------------------------------------------------------
__launch_bounds__(256)
__global__ void ychunk_k(const float* __restrict__ zx, const float* __restrict__ dtb,
                         const float* __restrict__ Bb, const float* __restrict__ Cb,
                         const float* __restrict__ acs, const float* __restrict__ prev,
                         const float* __restrict__ Dv, const int* __restrict__ mor,
                         u16* __restrict__ cat, int catOff)
{
    __shared__ float Xs[256][36];
    __shared__ float4 Bs[256];
    __shared__ float4 Cs[256];
    __shared__ float as_s[256];
    __shared__ float dt_s[256];
    __shared__ float4 pv_s[32];
    const int c = blockIdx.x, h = blockIdx.y, ph = blockIdx.z;
    const int l = threadIdx.x;
    const int gl = c * 256 + l;
    const bool valid = gl < L_SEQ;
    if (valid) {
        const float4* xrow = (const float4*)(zx + (size_t)gl * DPROJ + 256 + h * HD + ph * 32);
#pragma unroll
        for (int q = 0; q < 8; ++q) {
            float4 v = xrow[q];
            Xs[l][q * 4 + 0] = silu_f(v.x);
            Xs[l][q * 4 + 1] = silu_f(v.y);
            Xs[l][q * 4 + 2] = silu_f(v.z);
            Xs[l][q * 4 + 3] = silu_f(v.w);
        }
        Bs[l] = *(const float4*)(Bb + (size_t)gl * 4);
        Cs[l] = *(const float4*)(Cb + (size_t)gl * 4);
        as_s[l] = acs[(size_t)gl * 4 + h];
        dt_s[l] = dtb[(size_t)gl * 4 + h];
    } else {
#pragma unroll
        for (int q = 0; q < 32; ++q) Xs[l][q] = 0.f;
        Bs[l] = make_float4(0.f, 0.f, 0.f, 0.f);
        Cs[l] = make_float4(0.f, 0.f, 0.f, 0.f);
        as_s[l] = 0.f; dt_s[l] = 0.f;
    }
    if (l < 32)
        pv_s[l] = *(const float4*)(prev + ((size_t)(c * NH + h) * HD + ph * 32 + l) * 4);
    __syncthreads();

    float y[32];
#pragma unroll
    for (int p = 0; p < 32; ++p) y[p] = 0.f;
    const float4 cl = Cs[l];
    const float al = as_s[l];
    for (int s = 0; s < 256; ++s) {
        float4 bs = Bs[s];
        float w = cl.x * bs.x + cl.y * bs.y + cl.z * bs.z + cl.w * bs.w;
        w = (s <= l) ? w * __expf(al - as_s[s]) * dt_s[s] : 0.f;
        const float4* xr = (const float4*)(&Xs[s][0]);
#pragma unroll
        for (int q = 0; q < 8; ++q) {
            float4 xv = xr[q];
            y[q * 4 + 0] += w * xv.x;
            y[q * 4 + 1] += w * xv.y;
            y[q * 4 + 2] += w * xv.z;
            y[q * 4 + 3] += w * xv.w;
        }
    }
    if (valid) {
        const float eal = __expf(al);
        const float dco = Dv[h];
#pragma unroll
        for (int p = 0; p < 32; ++p) {
            float4 pp = pv_s[p];
            y[p] += eal * (cl.x * pp.x + cl.y * pp.y + cl.z * pp.z + cl.w * pp.w)
                  + dco * Xs[l][p];
        }
        const int pos = mor[gl];
        u16* orow = cat + (size_t)pos * 512 + catOff + h * HD + ph * 32;
        const float4* zrow = (const float4*)(zx + (size_t)gl * DPROJ + h * HD + ph * 32);
        union { u16 us[8]; uint4 v; } pk;
#pragma unroll
        for (int q2 = 0; q2 < 4; ++q2) {
            float4 z0 = zrow[q2 * 2], z1 = zrow[q2 * 2 + 1];
            pk.us[0] = f2bf(y[q2 * 8 + 0] * silu_f(z0.x));
            pk.us[1] = f2bf(y[q2 * 8 + 1] * silu_f(z0.y));
            pk.us[2] = f2bf(y[q2 * 8 + 2] * silu_f(z0.z));
            pk.us[3] = f2bf(y[q2 * 8 + 3] * silu_f(z0.w));
            pk.us[4] = f2bf(y[q2 * 8 + 4] * silu_f(z1.x));
            pk.us[5] = f2bf(y[q2 * 8 + 5] * silu_f(z1.y));
            pk.us[6] = f2bf(y[q2 * 8 + 6] * silu_f(z1.z));
            pk.us[7] = f2bf(y[q2 * 8 + 7] * silu_f(z1.w));
            *(uint4*)(orow + q2 * 8) = pk.v;
        }
    }
}

// ---------------------------------------------------------------------------
// LayerNorm over channel dim (256).
// ---------------------------------------------------------------------------
__launch_bounds__(256)
__global__ void ln_k(const float* __restrict__ pin, const float* __restrict__ g,
                     const float* __restrict__ b, float* __restrict__ pout)
{
    const int l = blockIdx.x, c = threadIdx.x;
    float v = pin[(size_t)l * 256 + c];
    float s = v, s2 = v * v;
#pragma unroll
    for (int o = 32; o > 0; o >>= 1) { s += __shfl_down(s, o); s2 += __shfl_down(s2, o); }
    __shared__ float ws0[4], ws1[4];
    if ((c & 63) == 0) { ws0[c >> 6] = s; ws1[c >> 6] = s2; }
    __syncthreads();
    float ts = ws0[0] + ws0[1] + ws0[2] + ws0[3];
    float t2 = ws1[0] + ws1[1] + ws1[2] + ws1[3];
    float mu = ts * (1.f / 256.f);
    float var = t2 * (1.f / 256.f) - mu * mu;
    float r = rsqrtf(var + 1e-6f);
    pout[(size_t)l * 256 + c] = (v - mu) * r * g[c] + b[c];
}

// ---------------------------------------------------------------------------
// Transpose (L x 256) -> (256 x L).
// ---------------------------------------------------------------------------
__global__ void transpose_k(const float* __restrict__ pin, float* __restrict__ pout)
{
    __shared__ float t[64][65];
    const int l0 = blockIdx.x * 64, c0 = blockIdx.y * 64;
    const int tx = threadIdx.x, ty = threadIdx.y;
#pragma unroll
    for (int j = 0; j < 16; ++j) {
        int row = ty + j * 4;
        int l = l0 + row;
        t[row][tx] = (l < L_SEQ) ? pin[(size_t)l * 256 + c0 + tx] : 0.f;
    }
    __syncthreads();
#pragma unroll
    for (int j = 0; j < 16; ++j) {
        int crow = ty + j * 4;
        int lcol = l0 + tx;
        if (lcol < L_SEQ) pout[(size_t)(c0 + crow) * L_SEQ + lcol] = t[tx][crow];
    }
}

// ---------------------------------------------------------------------------
extern "C" void kernel_launch(void* const* d_in, const int* in_sizes, int n_in,
                              void* d_out, int out_size, void* d_ws, size_t ws_size,
                              hipStream_t stream)
{
    const float* x        = (const float*)d_in[0];
    const float* W_in[2]  = {(const float*)d_in[1], (const float*)d_in[2]};
    const float* dt_b[2]  = {(const float*)d_in[3], (const float*)d_in[4]};
    const float* A_log[2] = {(const float*)d_in[5], (const float*)d_in[6]};
    const float* Dv[2]    = {(const float*)d_in[7], (const float*)d_in[8]};
    const float* W_out    = (const float*)d_in[9];
    const float* ln_g     = (const float*)d_in[10];
    const float* ln_b     = (const float*)d_in[11];
    const int*   mor[2]   = {(const int*)d_in[12], (const int*)d_in[13]};
    const int*   inv[2]   = {(const int*)d_in[14], (const int*)d_in[15]};

    char* ws = (char*)d_ws;
    size_t off = 0;
    auto alloc = [&](size_t bytes) { char* p = ws + off; off += (bytes + 255) & ~(size_t)255; return p; };
    float* zx    = (float*)alloc((size_t)L_SEQ * DPROJ * 4);   // reused as proj out
    u16*   cat   = (u16*)  alloc((size_t)MPAD * 512 * 2);      // bf16; reused (f32) as LN out
    u16*   xg    = (u16*)  alloc((size_t)MPAD * 256 * 2);
    u16*   wbuf  = (u16*)  alloc((size_t)640 * 256 * 2);
    float* dtb   = (float*)alloc((size_t)L_SEQ * 4 * 4);
    float* Bb    = (float*)alloc((size_t)L_SEQ * 4 * 4);
    float* Cb    = (float*)alloc((size_t)L_SEQ * 4 * 4);
    float* acsb  = (float*)alloc((size_t)L_SEQ * 4 * 4);
    float* csum  = (float*)alloc((size_t)NCH * 4 * 4);
    float* states= (float*)alloc((size_t)NCH * NH * HD * NST * 4);
    float* prev  = (float*)alloc((size_t)NCH * NH * HD * NST * 4);
    float* proj  = zx;           // zx dead after both paths
    float* lnout = (float*)cat;  // cat dead after out-proj

    for (int path = 0; path < 2; ++path) {
        convpad_k<<<640, 256, 0, stream>>>(W_in[path], wbuf, 524, 256, 640);
        gather_k<<<507, 256, 0, stream>>>(x, inv[path], xg);
        zero_k<<<(112 * 256 + 255) / 256, 256, 0, stream>>>(xg + (size_t)L_SEQ * 256, 112 * 256);
        mfma_gemm_k<<<dim3(254, 5), 256, 0, stream>>>(xg, wbuf, zx, 256, 524, L_SEQ, DPROJ);
        prep_k<<<NCH, 256, 0, stream>>>(zx, dt_b[path], A_log[path], dtb, Bb, Cb, acsb, csum);
        states_k<<<dim3(NCH, NH), 256, 0, stream>>>(zx, dtb, Bb, acsb, csum, states);
        chunkscan_k<<<1, 1024, 0, stream>>>(csum, states, prev);
        ychunk_k<<<dim3(NCH, NH, 2), 256, 0, stream>>>(zx, dtb, Bb, Cb, acsb, prev,
                                                       Dv[path], mor[path], cat, path * 256);
    }
    zero_k<<<(112 * 512 + 255) / 256, 256, 0, stream>>>(cat + (size_t)L_SEQ * 512, 112 * 512);
    convpad_k<<<256, 256, 0, stream>>>(W_out, wbuf, 256, 512, 256);
    mfma_gemm_k<<<dim3(254, 2), 256, 0, stream>>>(cat, wbuf, proj, 512, 256, L_SEQ, 256);
    ln_k<<<L_SEQ, 256, 0, stream>>>(proj, ln_g, ln_b, lnout);
    transpose_k<<<dim3(507, 4), dim3(64, 4), 0, stream>>>(lnout, (float*)d_out);
}

// Round 3
// 525.960 us; speedup vs baseline: 2.0785x; 1.2804x over previous
//
#include <hip/hip_runtime.h>
#include <cstdint>

#define L_SEQ 32400
#define HWSZ  32400
#define MPAD  32512
#define NCH   127
#define DPROJ 524
#define NH    4
#define HD    64
#define NST   4

typedef unsigned short u16;
typedef unsigned int   u32;
typedef __attribute__((ext_vector_type(8))) short short8;
typedef __attribute__((ext_vector_type(4))) float f32x4;

__device__ __forceinline__ float silu_f(float v) { return v / (1.f + __expf(-v)); }
__device__ __forceinline__ float softplus_f(float v) { return v > 20.f ? v : log1pf(__expf(v)); }
__device__ __forceinline__ u16 f2bf(float f) {
    u32 u = __float_as_uint(f);
    u += 0x7FFFu + ((u >> 16) & 1u);
    return (u16)(u >> 16);
}
__device__ __forceinline__ void gload16(const void* g, void* l) {
    __builtin_amdgcn_global_load_lds(
        (const __attribute__((address_space(1))) u32*)(uintptr_t)g,
        (__attribute__((address_space(3))) u32*)(u32)(uintptr_t)l,
        16, 0, 0);
}

// ---------------------------------------------------------------------------
// Gather + transpose + bf16 pack: xg[inv[pix]][c] = bf16(x[c][pix]).
// ---------------------------------------------------------------------------
__launch_bounds__(256)
__global__ void gather_k(const float* __restrict__ x, const int* __restrict__ inv,
                         u16* __restrict__ xg)
{
    __shared__ u16 tile[256][66];
    const int pix0 = blockIdx.x * 64;
    const int tid = threadIdx.x;
    const int pl = tid & 63, cq = tid >> 6;
    const int pix = pix0 + pl;
    const bool pv = pix < HWSZ;
#pragma unroll 4
    for (int j = 0; j < 64; ++j) {
        int c = cq * 64 + j;
        float v = pv ? x[(size_t)c * HWSZ + pix] : 0.f;
        tile[c][pl] = f2bf(v);
    }
    __syncthreads();
    for (int i = 0; i < 64; ++i) {
        int p2 = pix0 + i;
        if (p2 < HWSZ) {
            int row = inv[p2];
            xg[(size_t)row * 256 + tid] = tile[tid][i];
        }
    }
}

__global__ void zero_k(u16* __restrict__ p, int n)
{
    int i = blockIdx.x * 256 + threadIdx.x;
    if (i < n) p[i] = 0;
}

// Convert f32 [rows][cols] -> bf16 [rowsPad][cols], pad rows zeroed.
__global__ void convpad_k(const float* __restrict__ src, u16* __restrict__ dst,
                          int rows, int cols, int rowsPad)
{
    int r = blockIdx.x;
    for (int c = threadIdx.x; c < cols; c += 256)
        dst[(size_t)r * cols + c] = (r < rows) ? f2bf(src[(size_t)r * cols + c]) : (u16)0;
}

// ---------------------------------------------------------------------------
// bf16 MFMA GEMM: out[m][n] = sum_k A[m][k]*B[n][k]  (f32 out)
// 128x128 tile, BK=64, 4 waves, 16x16x32 MFMA, global_load_lds staging.
// ---------------------------------------------------------------------------
__launch_bounds__(256)
__global__ void mfma_gemm_k(const u16* __restrict__ A, const u16* __restrict__ B,
                            float* __restrict__ out, int K, int Nout, int M, int ldo)
{
    __shared__ u16 As[128 * 64];
    __shared__ u16 Bs[128 * 64];
    const int r0 = blockIdx.x * 128, c0 = blockIdx.y * 128;
    const int tid = threadIdx.x;
    const int lane = tid & 63, w = tid >> 6;
    const int wr = (w >> 1) * 64, wc = (w & 1) * 64;
    f32x4 acc[4][4];
#pragma unroll
    for (int m = 0; m < 4; ++m)
#pragma unroll
        for (int n = 0; n < 4; ++n)
            acc[m][n] = (f32x4){0.f, 0.f, 0.f, 0.f};

    const int rlane = lane & 15;
    const int khalf = (lane >> 4) * 16;

    for (int k0 = 0; k0 < K; k0 += 64) {
#pragma unroll
        for (int i = 0; i < 4; ++i) {
            int chunk = i * 256 + tid;
            int row = chunk >> 3, ks = chunk & 7;
            gload16(A + ((size_t)(r0 + row) * K + k0 + ks * 8), (char*)As + chunk * 16);
            gload16(B + ((size_t)(c0 + row) * K + k0 + ks * 8), (char*)Bs + chunk * 16);
        }
        __syncthreads();
#pragma unroll
        for (int ks = 0; ks < 2; ++ks) {
            short8 a[4], b[4];
#pragma unroll
            for (int m = 0; m < 4; ++m)
                a[m] = *(const short8*)((const char*)As + (wr + m * 16 + rlane) * 128 + ks * 64 + khalf);
#pragma unroll
            for (int n = 0; n < 4; ++n)
                b[n] = *(const short8*)((const char*)Bs + (wc + n * 16 + rlane) * 128 + ks * 64 + khalf);
#pragma unroll
            for (int m = 0; m < 4; ++m)
#pragma unroll
                for (int n = 0; n < 4; ++n)
                    acc[m][n] = __builtin_amdgcn_mfma_f32_16x16x32_bf16(a[m], b[n], acc[m][n], 0, 0, 0);
        }
        __syncthreads();
    }
    const int rl = (lane >> 4) * 4, cl = lane & 15;
#pragma unroll
    for (int m = 0; m < 4; ++m) {
#pragma unroll
        for (int n = 0; n < 4; ++n) {
            int col = c0 + wc + n * 16 + cl;
            if (col >= Nout) continue;
#pragma unroll
            for (int r = 0; r < 4; ++r) {
                int row = r0 + wr + m * 16 + rl + r;
                if (row < M) out[(size_t)row * ldo + col] = acc[m][n][r];
            }
        }
    }
}

// ---------------------------------------------------------------------------
// Per-chunk prep.
// ---------------------------------------------------------------------------
__launch_bounds__(256)
__global__ void prep_k(const float* __restrict__ zx, const float* __restrict__ dt_bias,
                       const float* __restrict__ A_log, float* __restrict__ dtb,
                       float* __restrict__ Bb, float* __restrict__ Cb,
                       float* __restrict__ acsb, float* __restrict__ csum)
{
    const int c = blockIdx.x;
    const int l = threadIdx.x;
    const int gl = c * 256 + l;
    const bool valid = gl < L_SEQ;
    float a[NH] = {0.f, 0.f, 0.f, 0.f};
    if (valid) {
        const float* row = zx + (size_t)gl * DPROJ;
        float4 bv = *(const float4*)(row + 512);
        float4 cv = *(const float4*)(row + 516);
        float4 dv = *(const float4*)(row + 520);
        Bb[(size_t)gl * 4 + 0] = silu_f(bv.x);
        Bb[(size_t)gl * 4 + 1] = silu_f(bv.y);
        Bb[(size_t)gl * 4 + 2] = silu_f(bv.z);
        Bb[(size_t)gl * 4 + 3] = silu_f(bv.w);
        Cb[(size_t)gl * 4 + 0] = silu_f(cv.x);
        Cb[(size_t)gl * 4 + 1] = silu_f(cv.y);
        Cb[(size_t)gl * 4 + 2] = silu_f(cv.z);
        Cb[(size_t)gl * 4 + 3] = silu_f(cv.w);
        const float* dp = (const float*)&dv;
#pragma unroll
        for (int h = 0; h < NH; ++h) {
            float dt = softplus_f(dp[h] + dt_bias[h]);
            dtb[(size_t)gl * 4 + h] = dt;
            a[h] = -__expf(A_log[h]) * dt;
        }
    }
    __shared__ float sb[256];
#pragma unroll 1
    for (int h = 0; h < NH; ++h) {
        float v = a[h];
        sb[l] = v;
        __syncthreads();
        for (int off = 1; off < 256; off <<= 1) {
            float t = (l >= off) ? sb[l - off] : 0.f;
            __syncthreads();
            v += t;
            sb[l] = v;
            __syncthreads();
        }
        if (valid) acsb[(size_t)gl * 4 + h] = v;
        if (l == 255) csum[c * 4 + h] = v;
        __syncthreads();
    }
}

// ---------------------------------------------------------------------------
// Chunk-end states.
// ---------------------------------------------------------------------------
__launch_bounds__(256)
__global__ void states_k(const float* __restrict__ zx, const float* __restrict__ dtb,
                         const float* __restrict__ Bb, const float* __restrict__ acs,
                         const float* __restrict__ csum, float* __restrict__ states)
{
    const int c = blockIdx.x, h = blockIdx.y;
    const int p = threadIdx.x >> 2, n = threadIdx.x & 3;
    const float cs = csum[c * 4 + h];
    float acc = 0.f;
    const int lmax = (c * 256 + 256 <= L_SEQ) ? 256 : (L_SEQ - c * 256);
    for (int l = 0; l < lmax; ++l) {
        const int gl = c * 256 + l;
        float xs = silu_f(zx[(size_t)gl * DPROJ + 256 + h * HD + p]);
        acc += Bb[(size_t)gl * 4 + n] * __expf(cs - acs[(size_t)gl * 4 + h])
             * dtb[(size_t)gl * 4 + h] * xs;
    }
    states[((size_t)(c * NH + h) * HD + p) * NST + n] = acc;
}

// ---------------------------------------------------------------------------
// Sequential inter-chunk scan.
// ---------------------------------------------------------------------------
__global__ void chunkscan_k(const float* __restrict__ csum, const float* __restrict__ states,
                            float* __restrict__ prev)
{
    const int tid = threadIdx.x;
    const int h = tid >> 8, pn = tid & 255;
    float run = 0.f;
    for (int c = 0; c < NCH; ++c) {
        prev[(size_t)(c * NH + h) * 256 + pn] = run;
        run = run * __expf(csum[c * 4 + h]) + states[(size_t)(c * NH + h) * 256 + pn];
    }
}

// ---------------------------------------------------------------------------
// MFMA per-chunk output.  One block per (chunk, head); 4 waves.
// Y = W @ X  with W[l][s] built in-registers as MFMA A-fragments:
//   W[l][s] = (C_l . B_s) * exp(acs_l - acs_s) * dt_s   (s <= l; +D on diag)
// X^T staged in LDS bf16 (64 x 256), XOR-swizzled.  Wave w owns row-frags
// m*64 + w*16 (balanced triangular work).  Epilogue adds exp(acs_l)*(C_l.prev),
// gates with silu(z), scatters bf16 rows into cat via morton.
// ---------------------------------------------------------------------------
__launch_bounds__(256)
__global__ void ychunk_mfma_k(const float* __restrict__ zx, const float* __restrict__ dtb,
                              const float* __restrict__ Bb, const float* __restrict__ Cb,
                              const float* __restrict__ acs, const float* __restrict__ prev,
                              const float* __restrict__ Dv, const int* __restrict__ mor,
                              u16* __restrict__ cat, int catOff)
{
    __shared__ __align__(16) u16 Xt[64 * 256];   // [p][s], swizzled, 32KB
    __shared__ float4 sB[256];
    __shared__ float4 sC[256];
    __shared__ float2 sAD[256];                  // {acs, dt}
    __shared__ float4 sPrev[64];

    const int c = blockIdx.x, h = blockIdx.y;
    const int tid = threadIdx.x;
    const int lane = tid & 63, w = tid >> 6;
    const float Dh = Dv[h];

    // ---- stage X^T (wave w covers s in [w*64, w*64+64), p = lane) ----
    {
        const int p = lane;
#pragma unroll
        for (int jq = 0; jq < 8; ++jq) {
            const int s0 = w * 64 + jq * 8;
            union { u16 us[8]; uint4 v4; } pk;
#pragma unroll
            for (int j = 0; j < 8; ++j) {
                int gl = c * 256 + s0 + j;
                float xv = (gl < L_SEQ) ? zx[(size_t)gl * DPROJ + 256 + h * HD + p] : 0.f;
                pk.us[j] = f2bf(silu_f(xv));
            }
            u32 off = (u32)(p * 512 + s0 * 2) ^ (u32)((p & 15) << 4);
            *(uint4*)((char*)Xt + off) = pk.v4;
        }
    }
    // ---- stage B/C/acs/dt/prev ----
    {
        const int s = tid;
        const int gl = c * 256 + s;
        if (gl < L_SEQ) {
            sB[s] = *(const float4*)(Bb + (size_t)gl * 4);
            sC[s] = *(const float4*)(Cb + (size_t)gl * 4);
            sAD[s] = make_float2(acs[(size_t)gl * 4 + h], dtb[(size_t)gl * 4 + h]);
        } else {
            sB[s] = make_float4(0.f, 0.f, 0.f, 0.f);
            sC[s] = make_float4(0.f, 0.f, 0.f, 0.f);
            sAD[s] = make_float2(0.f, 0.f);
        }
        if (tid < 64)
            sPrev[tid] = *(const float4*)(prev + ((size_t)(c * NH + h) * HD + tid) * 4);
    }
    __syncthreads();

    // ---- per-lane row constants (A-fragment rows: m*64 + w*16 + (lane&15)) ----
    const int rl15 = lane & 15, kg = lane >> 4;
    int lrow[4]; float4 C4[4]; float acsR[4];
#pragma unroll
    for (int m = 0; m < 4; ++m) {
        lrow[m] = m * 64 + w * 16 + rl15;
        C4[m] = sC[lrow[m]];
        acsR[m] = sAD[lrow[m]].x;
    }

    f32x4 acc[4][4];
#pragma unroll
    for (int m = 0; m < 4; ++m)
#pragma unroll
        for (int n = 0; n < 4; ++n)
            acc[m][n] = (f32x4){0.f, 0.f, 0.f, 0.f};

    for (int ks = 0; ks < 8; ++ks) {
        const int s0 = ks * 32 + kg * 8;
        // B-operand fragments from swizzled Xt
        short8 bf[4];
#pragma unroll
        for (int n = 0; n < 4; ++n) {
            int col = n * 16 + rl15;
            u32 off = (u32)(col * 512 + ks * 64 + kg * 16) ^ (u32)((col & 15) << 4);
            bf[n] = *(const short8*)((const char*)Xt + off);
        }
        // s-side data
        float4 Bsv[8]; float2 ad[8];
#pragma unroll
        for (int j = 0; j < 8; ++j) { Bsv[j] = sB[s0 + j]; ad[j] = sAD[s0 + j]; }
#pragma unroll
        for (int m = 0; m < 4; ++m) {
            if (ks * 32 <= m * 64 + w * 16 + 15) {   // wave-uniform triangular skip
                union { u16 us[8]; short8 v; } aw;
#pragma unroll
                for (int j = 0; j < 8; ++j) {
                    int s = s0 + j;
                    float dot = C4[m].x * Bsv[j].x + C4[m].y * Bsv[j].y
                              + C4[m].z * Bsv[j].z + C4[m].w * Bsv[j].w;
                    float v = dot * __expf(acsR[m] - ad[j].x) * ad[j].y;
                    v = (s <= lrow[m]) ? v : 0.f;
                    v = (s == lrow[m]) ? v + Dh : v;
                    aw.us[j] = f2bf(v);
                }
#pragma unroll
                for (int n = 0; n < 4; ++n)
                    acc[m][n] = __builtin_amdgcn_mfma_f32_16x16x32_bf16(aw.v, bf[n], acc[m][n], 0, 0, 0);
            }
        }
    }

    // ---- epilogue: prev contribution, gating, scatter ----
#pragma unroll
    for (int m = 0; m < 4; ++m) {
#pragma unroll
        for (int r = 0; r < 4; ++r) {
            const int row = m * 64 + w * 16 + kg * 4 + r;
            const int gl = c * 256 + row;
            const bool valid = gl < L_SEQ;
            const float4 Cr = sC[row];
            const float ea = __expf(sAD[row].x);
            const int pos = valid ? mor[gl] : 0;
            const float* zrow = zx + (size_t)gl * DPROJ + h * HD;
            u16* orow = cat + (size_t)pos * 512 + catOff + h * HD;
#pragma unroll
            for (int n = 0; n < 4; ++n) {
                const int col = n * 16 + rl15;
                float4 pv = sPrev[col];
                float y = acc[m][n][r]
                        + ea * (Cr.x * pv.x + Cr.y * pv.y + Cr.z * pv.z + Cr.w * pv.w);
                if (valid) {
                    float z = zrow[col];
                    orow[col] = f2bf(y * silu_f(z));
                }
            }
        }
    }
}

// ---------------------------------------------------------------------------
// LayerNorm over channel dim (256).
// ---------------------------------------------------------------------------
__launch_bounds__(256)
__global__ void ln_k(const float* __restrict__ pin, const float* __restrict__ g,
                     const float* __restrict__ b, float* __restrict__ pout)
{
    const int l = blockIdx.x, c = threadIdx.x;
    float v = pin[(size_t)l * 256 + c];
    float s = v, s2 = v * v;
#pragma unroll
    for (int o = 32; o > 0; o >>= 1) { s += __shfl_down(s, o); s2 += __shfl_down(s2, o); }
    __shared__ float ws0[4], ws1[4];
    if ((c & 63) == 0) { ws0[c >> 6] = s; ws1[c >> 6] = s2; }
    __syncthreads();
    float ts = ws0[0] + ws0[1] + ws0[2] + ws0[3];
    float t2 = ws1[0] + ws1[1] + ws1[2] + ws1[3];
    float mu = ts * (1.f / 256.f);
    float var = t2 * (1.f / 256.f) - mu * mu;
    float r = rsqrtf(var + 1e-6f);
    pout[(size_t)l * 256 + c] = (v - mu) * r * g[c] + b[c];
}

// ---------------------------------------------------------------------------
// Transpose (L x 256) -> (256 x L).
// ---------------------------------------------------------------------------
__global__ void transpose_k(const float* __restrict__ pin, float* __restrict__ pout)
{
    __shared__ float t[64][65];
    const int l0 = blockIdx.x * 64, c0 = blockIdx.y * 64;
    const int tx = threadIdx.x, ty = threadIdx.y;
#pragma unroll
    for (int j = 0; j < 16; ++j) {
        int row = ty + j * 4;
        int l = l0 + row;
        t[row][tx] = (l < L_SEQ) ? pin[(size_t)l * 256 + c0 + tx] : 0.f;
    }
    __syncthreads();
#pragma unroll
    for (int j = 0; j < 16; ++j) {
        int crow = ty + j * 4;
        int lcol = l0 + tx;
        if (lcol < L_SEQ) pout[(size_t)(c0 + crow) * L_SEQ + lcol] = t[tx][crow];
    }
}

// ---------------------------------------------------------------------------
extern "C" void kernel_launch(void* const* d_in, const int* in_sizes, int n_in,
                              void* d_out, int out_size, void* d_ws, size_t ws_size,
                              hipStream_t stream)
{
    const float* x        = (const float*)d_in[0];
    const float* W_in[2]  = {(const float*)d_in[1], (const float*)d_in[2]};
    const float* dt_b[2]  = {(const float*)d_in[3], (const float*)d_in[4]};
    const float* A_log[2] = {(const float*)d_in[5], (const float*)d_in[6]};
    const float* Dv[2]    = {(const float*)d_in[7], (const float*)d_in[8]};
    const float* W_out    = (const float*)d_in[9];
    const float* ln_g     = (const float*)d_in[10];
    const float* ln_b     = (const float*)d_in[11];
    const int*   mor[2]   = {(const int*)d_in[12], (const int*)d_in[13]};
    const int*   inv[2]   = {(const int*)d_in[14], (const int*)d_in[15]};

    char* ws = (char*)d_ws;
    size_t off = 0;
    auto alloc = [&](size_t bytes) { char* p = ws + off; off += (bytes + 255) & ~(size_t)255; return p; };
    float* zx    = (float*)alloc((size_t)L_SEQ * DPROJ * 4);   // reused as proj out
    u16*   cat   = (u16*)  alloc((size_t)MPAD * 512 * 2);      // bf16; reused (f32) as LN out
    u16*   xg    = (u16*)  alloc((size_t)MPAD * 256 * 2);
    u16*   wbuf  = (u16*)  alloc((size_t)640 * 256 * 2);
    float* dtb   = (float*)alloc((size_t)L_SEQ * 4 * 4);
    float* Bb    = (float*)alloc((size_t)L_SEQ * 4 * 4);
    float* Cb    = (float*)alloc((size_t)L_SEQ * 4 * 4);
    float* acsb  = (float*)alloc((size_t)L_SEQ * 4 * 4);
    float* csum  = (float*)alloc((size_t)NCH * 4 * 4);
    float* states= (float*)alloc((size_t)NCH * NH * HD * NST * 4);
    float* prev  = (float*)alloc((size_t)NCH * NH * HD * NST * 4);
    float* proj  = zx;           // zx dead after both paths
    float* lnout = (float*)cat;  // cat dead after out-proj

    for (int path = 0; path < 2; ++path) {
        convpad_k<<<640, 256, 0, stream>>>(W_in[path], wbuf, 524, 256, 640);
        gather_k<<<507, 256, 0, stream>>>(x, inv[path], xg);
        zero_k<<<(112 * 256 + 255) / 256, 256, 0, stream>>>(xg + (size_t)L_SEQ * 256, 112 * 256);
        mfma_gemm_k<<<dim3(254, 5), 256, 0, stream>>>(xg, wbuf, zx, 256, 524, L_SEQ, DPROJ);
        prep_k<<<NCH, 256, 0, stream>>>(zx, dt_b[path], A_log[path], dtb, Bb, Cb, acsb, csum);
        states_k<<<dim3(NCH, NH), 256, 0, stream>>>(zx, dtb, Bb, acsb, csum, states);
        chunkscan_k<<<1, 1024, 0, stream>>>(csum, states, prev);
        ychunk_mfma_k<<<dim3(NCH, NH), 256, 0, stream>>>(zx, dtb, Bb, Cb, acsb, prev,
                                                         Dv[path], mor[path], cat, path * 256);
    }
    zero_k<<<(112 * 512 + 255) / 256, 256, 0, stream>>>(cat + (size_t)L_SEQ * 512, 112 * 512);
    convpad_k<<<256, 256, 0, stream>>>(W_out, wbuf, 256, 512, 256);
    mfma_gemm_k<<<dim3(254, 2), 256, 0, stream>>>(cat, wbuf, proj, 512, 256, L_SEQ, 256);
    ln_k<<<L_SEQ, 256, 0, stream>>>(proj, ln_g, ln_b, lnout);
    transpose_k<<<dim3(507, 4), dim3(64, 4), 0, stream>>>(lnout, (float*)d_out);
}

// Round 4
// 389.053 us; speedup vs baseline: 2.8100x; 1.3519x over previous
//
#include <hip/hip_runtime.h>
#include <cstdint>

#define L_SEQ 32400
#define HWSZ  32400
#define MPAD  32512
#define NCH   127
#define DPROJ 524
#define NH    4
#define HD    64
#define NST   4

typedef unsigned short u16;
typedef unsigned int   u32;
typedef __attribute__((ext_vector_type(8))) short short8;
typedef __attribute__((ext_vector_type(4))) float f32x4;

__device__ __forceinline__ float silu_f(float v) { return v / (1.f + __expf(-v)); }
__device__ __forceinline__ float softplus_f(float v) { return v > 20.f ? v : log1pf(__expf(v)); }
__device__ __forceinline__ u16 f2bf(float f) {
    u32 u = __float_as_uint(f);
    u += 0x7FFFu + ((u >> 16) & 1u);
    return (u16)(u >> 16);
}
__device__ __forceinline__ void gload16(const void* g, void* l) {
    __builtin_amdgcn_global_load_lds(
        (const __attribute__((address_space(1))) u32*)(uintptr_t)g,
        (__attribute__((address_space(3))) u32*)(u32)(uintptr_t)l,
        16, 0, 0);
}

// ---------------------------------------------------------------------------
// Gather + transpose + bf16 pack: xg[inv[pix]][c] = bf16(x[c][pix]).
// ---------------------------------------------------------------------------
__launch_bounds__(256)
__global__ void gather_k(const float* __restrict__ x, const int* __restrict__ inv,
                         u16* __restrict__ xg)
{
    __shared__ u16 tile[256][66];
    const int pix0 = blockIdx.x * 64;
    const int tid = threadIdx.x;
    const int pl = tid & 63, cq = tid >> 6;
    const int pix = pix0 + pl;
    const bool pv = pix < HWSZ;
#pragma unroll 4
    for (int j = 0; j < 64; ++j) {
        int c = cq * 64 + j;
        float v = pv ? x[(size_t)c * HWSZ + pix] : 0.f;
        tile[c][pl] = f2bf(v);
    }
    __syncthreads();
    for (int i = 0; i < 64; ++i) {
        int p2 = pix0 + i;
        if (p2 < HWSZ) {
            int row = inv[p2];
            xg[(size_t)row * 256 + tid] = tile[tid][i];
        }
    }
}

__global__ void zero_k(u16* __restrict__ p, int n)
{
    int i = blockIdx.x * 256 + threadIdx.x;
    if (i < n) p[i] = 0;
}

// Convert f32 [rows][cols] -> bf16 [rowsPad][cols], pad rows zeroed.
__global__ void convpad_k(const float* __restrict__ src, u16* __restrict__ dst,
                          int rows, int cols, int rowsPad)
{
    int r = blockIdx.x;
    for (int c = threadIdx.x; c < cols; c += 256)
        dst[(size_t)r * cols + c] = (r < rows) ? f2bf(src[(size_t)r * cols + c]) : (u16)0;
}

// ---------------------------------------------------------------------------
// bf16 MFMA GEMM: out[m][n] = sum_k A[m][k]*B[n][k]  (f32 out)
// ---------------------------------------------------------------------------
__launch_bounds__(256)
__global__ void mfma_gemm_k(const u16* __restrict__ A, const u16* __restrict__ B,
                            float* __restrict__ out, int K, int Nout, int M, int ldo)
{
    __shared__ u16 As[128 * 64];
    __shared__ u16 Bs[128 * 64];
    const int r0 = blockIdx.x * 128, c0 = blockIdx.y * 128;
    const int tid = threadIdx.x;
    const int lane = tid & 63, w = tid >> 6;
    const int wr = (w >> 1) * 64, wc = (w & 1) * 64;
    f32x4 acc[4][4];
#pragma unroll
    for (int m = 0; m < 4; ++m)
#pragma unroll
        for (int n = 0; n < 4; ++n)
            acc[m][n] = (f32x4){0.f, 0.f, 0.f, 0.f};

    const int rlane = lane & 15;
    const int khalf = (lane >> 4) * 16;

    for (int k0 = 0; k0 < K; k0 += 64) {
#pragma unroll
        for (int i = 0; i < 4; ++i) {
            int chunk = i * 256 + tid;
            int row = chunk >> 3, ks = chunk & 7;
            gload16(A + ((size_t)(r0 + row) * K + k0 + ks * 8), (char*)As + chunk * 16);
            gload16(B + ((size_t)(c0 + row) * K + k0 + ks * 8), (char*)Bs + chunk * 16);
        }
        __syncthreads();
#pragma unroll
        for (int ks = 0; ks < 2; ++ks) {
            short8 a[4], b[4];
#pragma unroll
            for (int m = 0; m < 4; ++m)
                a[m] = *(const short8*)((const char*)As + (wr + m * 16 + rlane) * 128 + ks * 64 + khalf);
#pragma unroll
            for (int n = 0; n < 4; ++n)
                b[n] = *(const short8*)((const char*)Bs + (wc + n * 16 + rlane) * 128 + ks * 64 + khalf);
#pragma unroll
            for (int m = 0; m < 4; ++m)
#pragma unroll
                for (int n = 0; n < 4; ++n)
                    acc[m][n] = __builtin_amdgcn_mfma_f32_16x16x32_bf16(a[m], b[n], acc[m][n], 0, 0, 0);
        }
        __syncthreads();
    }
    const int rl = (lane >> 4) * 4, cl = lane & 15;
#pragma unroll
    for (int m = 0; m < 4; ++m) {
#pragma unroll
        for (int n = 0; n < 4; ++n) {
            int col = c0 + wc + n * 16 + cl;
            if (col >= Nout) continue;
#pragma unroll
            for (int r = 0; r < 4; ++r) {
                int row = r0 + wr + m * 16 + rl + r;
                if (row < M) out[(size_t)row * ldo + col] = acc[m][n][r];
            }
        }
    }
}

// ---------------------------------------------------------------------------
// Per-chunk prep: silu(B/C), dt=softplus, a-cumsum via wave shuffle scan.
// One barrier total.
// ---------------------------------------------------------------------------
__launch_bounds__(256)
__global__ void prep_k(const float* __restrict__ zx, const float* __restrict__ dt_bias,
                       const float* __restrict__ A_log, float* __restrict__ dtb,
                       float* __restrict__ Bb, float* __restrict__ Cb,
                       float* __restrict__ acsb, float* __restrict__ csum)
{
    const int c = blockIdx.x;
    const int l = threadIdx.x;
    const int lane = l & 63, w = l >> 6;
    const int gl = c * 256 + l;
    const bool valid = gl < L_SEQ;
    float v[NH] = {0.f, 0.f, 0.f, 0.f};
    if (valid) {
        const float* row = zx + (size_t)gl * DPROJ;
        float4 bv = *(const float4*)(row + 512);
        float4 cv = *(const float4*)(row + 516);
        float4 dv = *(const float4*)(row + 520);
        Bb[(size_t)gl * 4 + 0] = silu_f(bv.x);
        Bb[(size_t)gl * 4 + 1] = silu_f(bv.y);
        Bb[(size_t)gl * 4 + 2] = silu_f(bv.z);
        Bb[(size_t)gl * 4 + 3] = silu_f(bv.w);
        Cb[(size_t)gl * 4 + 0] = silu_f(cv.x);
        Cb[(size_t)gl * 4 + 1] = silu_f(cv.y);
        Cb[(size_t)gl * 4 + 2] = silu_f(cv.z);
        Cb[(size_t)gl * 4 + 3] = silu_f(cv.w);
        const float* dp = (const float*)&dv;
#pragma unroll
        for (int h = 0; h < NH; ++h) {
            float dt = softplus_f(dp[h] + dt_bias[h]);
            dtb[(size_t)gl * 4 + h] = dt;
            v[h] = -__expf(A_log[h]) * dt;
        }
    }
    // wave-level inclusive scan (64 lanes)
#pragma unroll
    for (int off = 1; off < 64; off <<= 1) {
#pragma unroll
        for (int h = 0; h < NH; ++h) {
            float t = __shfl_up(v[h], off, 64);
            if (lane >= off) v[h] += t;
        }
    }
    __shared__ float wsum[4][NH];
    if (lane == 63)
#pragma unroll
        for (int h = 0; h < NH; ++h) wsum[w][h] = v[h];
    __syncthreads();
#pragma unroll
    for (int h = 0; h < NH; ++h) {
        float o = 0.f;
#pragma unroll
        for (int w2 = 0; w2 < 4; ++w2) if (w2 < w) o += wsum[w2][h];
        v[h] += o;
    }
    if (valid)
#pragma unroll
        for (int h = 0; h < NH; ++h) acsb[(size_t)gl * 4 + h] = v[h];
    if (l == 255)
#pragma unroll
        for (int h = 0; h < NH; ++h) csum[c * 4 + h] = v[h];
}

// ---------------------------------------------------------------------------
// Chunk-end states, partial: grid (NCH, 4 l-quarters), 256 threads (h,p).
// Phase 1: coef[l][h][n] = B[l,n]*exp(cs_h - acs[l,h])*dt[l,h] into LDS.
// Phase 2: coalesced x reads (1KB/iter/block), 4 FMA/thread/iter.
// ---------------------------------------------------------------------------
__launch_bounds__(256)
__global__ void states_part_k(const float* __restrict__ zx, const float* __restrict__ dtb,
                              const float* __restrict__ Bb, const float* __restrict__ acs,
                              const float* __restrict__ csum, float* __restrict__ spart)
{
    __shared__ float coef[64][16];
    const int c = blockIdx.x, q = blockIdx.y;
    const int tid = threadIdx.x;
    // phase 1: tid -> (l_loc = tid>>2, h = tid&3)
    {
        const int l_loc = tid >> 2, h = tid & 3;
        const int gl = c * 256 + q * 64 + l_loc;
        float4 Bv = make_float4(0.f, 0.f, 0.f, 0.f);
        float e = 0.f;
        if (gl < L_SEQ) {
            Bv = *(const float4*)(Bb + (size_t)gl * 4);
            e = __expf(csum[c * 4 + h] - acs[(size_t)gl * 4 + h]) * dtb[(size_t)gl * 4 + h];
        }
        float4 cf = make_float4(Bv.x * e, Bv.y * e, Bv.z * e, Bv.w * e);
        *(float4*)&coef[l_loc][h * 4] = cf;
    }
    __syncthreads();
    // phase 2: tid = h*64 + p; x col = 256 + tid
    const int h = tid >> 6;
    f32x4 acc = (f32x4){0.f, 0.f, 0.f, 0.f};
#pragma unroll 4
    for (int j = 0; j < 64; ++j) {
        const int gl = c * 256 + q * 64 + j;
        float xv = (gl < L_SEQ) ? zx[(size_t)gl * DPROJ + 256 + tid] : 0.f;
        float xs = silu_f(xv);
        float4 cf = *(const float4*)&coef[j][h * 4];
        acc[0] += cf.x * xs; acc[1] += cf.y * xs;
        acc[2] += cf.z * xs; acc[3] += cf.w * xs;
    }
    *(f32x4*)(spart + ((size_t)(c * 4 + q) * 256 + tid) * 4) = acc;
}

// ---------------------------------------------------------------------------
// Inter-chunk scan with fused q-reduction. grid 4 (h), 256 threads (p*4+n).
// prev[c] written BEFORE update: prev[c+1] = exp(csum_c)*prev[c] + states_c.
// ---------------------------------------------------------------------------
__launch_bounds__(256)
__global__ void chunkscan_k(const float* __restrict__ csum, const float* __restrict__ spart,
                            float* __restrict__ prev)
{
    const int h = blockIdx.x;
    const int tid = threadIdx.x;
    __shared__ float ecs[NCH];
    if (tid < NCH) ecs[tid] = __expf(csum[tid * 4 + h]);
    __syncthreads();
    float run = 0.f;
#pragma unroll 2
    for (int c = 0; c < NCH; ++c) {
        const float* sp = spart + (size_t)(c * 4) * 1024 + h * 256 + tid;
        float s = sp[0] + sp[1024] + sp[2048] + sp[3072];
        prev[(size_t)c * 1024 + h * 256 + tid] = run;
        run = run * ecs[c] + s;
    }
}

// ---------------------------------------------------------------------------
// MFMA per-chunk output (unchanged from round 2).
// ---------------------------------------------------------------------------
__launch_bounds__(256)
__global__ void ychunk_mfma_k(const float* __restrict__ zx, const float* __restrict__ dtb,
                              const float* __restrict__ Bb, const float* __restrict__ Cb,
                              const float* __restrict__ acs, const float* __restrict__ prev,
                              const float* __restrict__ Dv, const int* __restrict__ mor,
                              u16* __restrict__ cat, int catOff)
{
    __shared__ __align__(16) u16 Xt[64 * 256];
    __shared__ float4 sB[256];
    __shared__ float4 sC[256];
    __shared__ float2 sAD[256];
    __shared__ float4 sPrev[64];

    const int c = blockIdx.x, h = blockIdx.y;
    const int tid = threadIdx.x;
    const int lane = tid & 63, w = tid >> 6;
    const float Dh = Dv[h];

    {
        const int p = lane;
#pragma unroll
        for (int jq = 0; jq < 8; ++jq) {
            const int s0 = w * 64 + jq * 8;
            union { u16 us[8]; uint4 v4; } pk;
#pragma unroll
            for (int j = 0; j < 8; ++j) {
                int gl = c * 256 + s0 + j;
                float xv = (gl < L_SEQ) ? zx[(size_t)gl * DPROJ + 256 + h * HD + p] : 0.f;
                pk.us[j] = f2bf(silu_f(xv));
            }
            u32 off = (u32)(p * 512 + s0 * 2) ^ (u32)((p & 15) << 4);
            *(uint4*)((char*)Xt + off) = pk.v4;
        }
    }
    {
        const int s = tid;
        const int gl = c * 256 + s;
        if (gl < L_SEQ) {
            sB[s] = *(const float4*)(Bb + (size_t)gl * 4);
            sC[s] = *(const float4*)(Cb + (size_t)gl * 4);
            sAD[s] = make_float2(acs[(size_t)gl * 4 + h], dtb[(size_t)gl * 4 + h]);
        } else {
            sB[s] = make_float4(0.f, 0.f, 0.f, 0.f);
            sC[s] = make_float4(0.f, 0.f, 0.f, 0.f);
            sAD[s] = make_float2(0.f, 0.f);
        }
        if (tid < 64)
            sPrev[tid] = *(const float4*)(prev + ((size_t)(c * NH + h) * HD + tid) * 4);
    }
    __syncthreads();

    const int rl15 = lane & 15, kg = lane >> 4;
    int lrow[4]; float4 C4[4]; float acsR[4];
#pragma unroll
    for (int m = 0; m < 4; ++m) {
        lrow[m] = m * 64 + w * 16 + rl15;
        C4[m] = sC[lrow[m]];
        acsR[m] = sAD[lrow[m]].x;
    }

    f32x4 acc[4][4];
#pragma unroll
    for (int m = 0; m < 4; ++m)
#pragma unroll
        for (int n = 0; n < 4; ++n)
            acc[m][n] = (f32x4){0.f, 0.f, 0.f, 0.f};

    for (int ks = 0; ks < 8; ++ks) {
        const int s0 = ks * 32 + kg * 8;
        short8 bf[4];
#pragma unroll
        for (int n = 0; n < 4; ++n) {
            int col = n * 16 + rl15;
            u32 off = (u32)(col * 512 + ks * 64 + kg * 16) ^ (u32)((col & 15) << 4);
            bf[n] = *(const short8*)((const char*)Xt + off);
        }
        float4 Bsv[8]; float2 ad[8];
#pragma unroll
        for (int j = 0; j < 8; ++j) { Bsv[j] = sB[s0 + j]; ad[j] = sAD[s0 + j]; }
#pragma unroll
        for (int m = 0; m < 4; ++m) {
            if (ks * 32 <= m * 64 + w * 16 + 15) {
                union { u16 us[8]; short8 v; } aw;
#pragma unroll
                for (int j = 0; j < 8; ++j) {
                    int s = s0 + j;
                    float dot = C4[m].x * Bsv[j].x + C4[m].y * Bsv[j].y
                              + C4[m].z * Bsv[j].z + C4[m].w * Bsv[j].w;
                    float vv = dot * __expf(acsR[m] - ad[j].x) * ad[j].y;
                    vv = (s <= lrow[m]) ? vv : 0.f;
                    vv = (s == lrow[m]) ? vv + Dh : vv;
                    aw.us[j] = f2bf(vv);
                }
#pragma unroll
                for (int n = 0; n < 4; ++n)
                    acc[m][n] = __builtin_amdgcn_mfma_f32_16x16x32_bf16(aw.v, bf[n], acc[m][n], 0, 0, 0);
            }
        }
    }

#pragma unroll
    for (int m = 0; m < 4; ++m) {
#pragma unroll
        for (int r = 0; r < 4; ++r) {
            const int row = m * 64 + w * 16 + kg * 4 + r;
            const int gl = c * 256 + row;
            const bool valid = gl < L_SEQ;
            const float4 Cr = sC[row];
            const float ea = __expf(sAD[row].x);
            const int pos = valid ? mor[gl] : 0;
            const float* zrow = zx + (size_t)gl * DPROJ + h * HD;
            u16* orow = cat + (size_t)pos * 512 + catOff + h * HD;
#pragma unroll
            for (int n = 0; n < 4; ++n) {
                const int col = n * 16 + rl15;
                float4 pv = sPrev[col];
                float y = acc[m][n][r]
                        + ea * (Cr.x * pv.x + Cr.y * pv.y + Cr.z * pv.z + Cr.w * pv.w);
                if (valid) {
                    float z = zrow[col];
                    orow[col] = f2bf(y * silu_f(z));
                }
            }
        }
    }
}

// ---------------------------------------------------------------------------
// LayerNorm over channel dim (256).
// ---------------------------------------------------------------------------
__launch_bounds__(256)
__global__ void ln_k(const float* __restrict__ pin, const float* __restrict__ g,
                     const float* __restrict__ b, float* __restrict__ pout)
{
    const int l = blockIdx.x, c = threadIdx.x;
    float v = pin[(size_t)l * 256 + c];
    float s = v, s2 = v * v;
#pragma unroll
    for (int o = 32; o > 0; o >>= 1) { s += __shfl_down(s, o); s2 += __shfl_down(s2, o); }
    __shared__ float ws0[4], ws1[4];
    if ((c & 63) == 0) { ws0[c >> 6] = s; ws1[c >> 6] = s2; }
    __syncthreads();
    float ts = ws0[0] + ws0[1] + ws0[2] + ws0[3];
    float t2 = ws1[0] + ws1[1] + ws1[2] + ws1[3];
    float mu = ts * (1.f / 256.f);
    float var = t2 * (1.f / 256.f) - mu * mu;
    float r = rsqrtf(var + 1e-6f);
    pout[(size_t)l * 256 + c] = (v - mu) * r * g[c] + b[c];
}

// ---------------------------------------------------------------------------
// Transpose (L x 256) -> (256 x L).
// ---------------------------------------------------------------------------
__global__ void transpose_k(const float* __restrict__ pin, float* __restrict__ pout)
{
    __shared__ float t[64][65];
    const int l0 = blockIdx.x * 64, c0 = blockIdx.y * 64;
    const int tx = threadIdx.x, ty = threadIdx.y;
#pragma unroll
    for (int j = 0; j < 16; ++j) {
        int row = ty + j * 4;
        int l = l0 + row;
        t[row][tx] = (l < L_SEQ) ? pin[(size_t)l * 256 + c0 + tx] : 0.f;
    }
    __syncthreads();
#pragma unroll
    for (int j = 0; j < 16; ++j) {
        int crow = ty + j * 4;
        int lcol = l0 + tx;
        if (lcol < L_SEQ) pout[(size_t)(c0 + crow) * L_SEQ + lcol] = t[tx][crow];
    }
}

// ---------------------------------------------------------------------------
extern "C" void kernel_launch(void* const* d_in, const int* in_sizes, int n_in,
                              void* d_out, int out_size, void* d_ws, size_t ws_size,
                              hipStream_t stream)
{
    const float* x        = (const float*)d_in[0];
    const float* W_in[2]  = {(const float*)d_in[1], (const float*)d_in[2]};
    const float* dt_b[2]  = {(const float*)d_in[3], (const float*)d_in[4]};
    const float* A_log[2] = {(const float*)d_in[5], (const float*)d_in[6]};
    const float* Dv[2]    = {(const float*)d_in[7], (const float*)d_in[8]};
    const float* W_out    = (const float*)d_in[9];
    const float* ln_g     = (const float*)d_in[10];
    const float* ln_b     = (const float*)d_in[11];
    const int*   mor[2]   = {(const int*)d_in[12], (const int*)d_in[13]};
    const int*   inv[2]   = {(const int*)d_in[14], (const int*)d_in[15]};

    char* ws = (char*)d_ws;
    size_t off = 0;
    auto alloc = [&](size_t bytes) { char* p = ws + off; off += (bytes + 255) & ~(size_t)255; return p; };
    float* zx    = (float*)alloc((size_t)L_SEQ * DPROJ * 4);   // reused as proj out
    u16*   cat   = (u16*)  alloc((size_t)MPAD * 512 * 2);      // bf16; reused (f32) as LN out
    u16*   xg    = (u16*)  alloc((size_t)MPAD * 256 * 2);
    u16*   wbuf  = (u16*)  alloc((size_t)640 * 256 * 2);
    float* dtb   = (float*)alloc((size_t)L_SEQ * 4 * 4);
    float* Bb    = (float*)alloc((size_t)L_SEQ * 4 * 4);
    float* Cb    = (float*)alloc((size_t)L_SEQ * 4 * 4);
    float* acsb  = (float*)alloc((size_t)L_SEQ * 4 * 4);
    float* csum  = (float*)alloc((size_t)NCH * 4 * 4);
    float* spart = (float*)alloc((size_t)NCH * 4 * 1024 * 4);
    float* prev  = (float*)alloc((size_t)NCH * 1024 * 4);
    float* proj  = zx;           // zx dead after both paths
    float* lnout = (float*)cat;  // cat dead after out-proj

    for (int path = 0; path < 2; ++path) {
        convpad_k<<<640, 256, 0, stream>>>(W_in[path], wbuf, 524, 256, 640);
        gather_k<<<507, 256, 0, stream>>>(x, inv[path], xg);
        zero_k<<<(112 * 256 + 255) / 256, 256, 0, stream>>>(xg + (size_t)L_SEQ * 256, 112 * 256);
        mfma_gemm_k<<<dim3(254, 5), 256, 0, stream>>>(xg, wbuf, zx, 256, 524, L_SEQ, DPROJ);
        prep_k<<<NCH, 256, 0, stream>>>(zx, dt_b[path], A_log[path], dtb, Bb, Cb, acsb, csum);
        states_part_k<<<dim3(NCH, 4), 256, 0, stream>>>(zx, dtb, Bb, acsb, csum, spart);
        chunkscan_k<<<4, 256, 0, stream>>>(csum, spart, prev);
        ychunk_mfma_k<<<dim3(NCH, NH), 256, 0, stream>>>(zx, dtb, Bb, Cb, acsb, prev,
                                                         Dv[path], mor[path], cat, path * 256);
    }
    zero_k<<<(112 * 512 + 255) / 256, 256, 0, stream>>>(cat + (size_t)L_SEQ * 512, 112 * 512);
    convpad_k<<<256, 256, 0, stream>>>(W_out, wbuf, 256, 512, 256);
    mfma_gemm_k<<<dim3(254, 2), 256, 0, stream>>>(cat, wbuf, proj, 512, 256, L_SEQ, 256);
    ln_k<<<L_SEQ, 256, 0, stream>>>(proj, ln_g, ln_b, lnout);
    transpose_k<<<dim3(507, 4), dim3(64, 4), 0, stream>>>(lnout, (float*)d_out);
}

// Round 5
// 373.273 us; speedup vs baseline: 2.9287x; 1.0423x over previous
//
#include <hip/hip_runtime.h>
#include <cstdint>

#define L_SEQ 32400
#define HWSZ  32400
#define MPAD  32512
#define NCH   127
#define DPROJ 524
#define NH    4
#define HD    64
#define NST   4
#define LOG2E 1.4426950408889634f

typedef unsigned short u16;
typedef unsigned int   u32;
typedef __attribute__((ext_vector_type(8))) short short8;
typedef __attribute__((ext_vector_type(4))) float f32x4;

__device__ __forceinline__ float silu_f(float v) { return v / (1.f + __expf(-v)); }
__device__ __forceinline__ float softplus_f(float v) { return v > 20.f ? v : log1pf(__expf(v)); }
__device__ __forceinline__ u16 f2bf(float f) {
    u32 u = __float_as_uint(f);
    u += 0x7FFFu + ((u >> 16) & 1u);
    return (u16)(u >> 16);
}
__device__ __forceinline__ u32 cvtpk(float lo, float hi) {
    u32 r;
    asm("v_cvt_pk_bf16_f32 %0, %1, %2" : "=v"(r) : "v"(lo), "v"(hi));
    return r;
}
__device__ __forceinline__ void gload16(const void* g, void* l) {
    __builtin_amdgcn_global_load_lds(
        (const __attribute__((address_space(1))) u32*)(uintptr_t)g,
        (__attribute__((address_space(3))) u32*)(u32)(uintptr_t)l,
        16, 0, 0);
}

// ---------------------------------------------------------------------------
// Gather + transpose + bf16 pack: xg[inv[pix]][c] = bf16(x[c][pix]).
// ---------------------------------------------------------------------------
__launch_bounds__(256)
__global__ void gather_k(const float* __restrict__ x, const int* __restrict__ inv,
                         u16* __restrict__ xg)
{
    __shared__ u16 tile[256][66];
    const int pix0 = blockIdx.x * 64;
    const int tid = threadIdx.x;
    const int pl = tid & 63, cq = tid >> 6;
    const int pix = pix0 + pl;
    const bool pv = pix < HWSZ;
#pragma unroll 4
    for (int j = 0; j < 64; ++j) {
        int c = cq * 64 + j;
        float v = pv ? x[(size_t)c * HWSZ + pix] : 0.f;
        tile[c][pl] = f2bf(v);
    }
    __syncthreads();
    for (int i = 0; i < 64; ++i) {
        int p2 = pix0 + i;
        if (p2 < HWSZ) {
            int row = inv[p2];
            xg[(size_t)row * 256 + tid] = tile[tid][i];
        }
    }
}

__global__ void zero_k(u16* __restrict__ p, int n)
{
    int i = blockIdx.x * 256 + threadIdx.x;
    if (i < n) p[i] = 0;
}

// Convert f32 [rows][cols] -> bf16 [rowsPad][cols], pad rows zeroed.
__global__ void convpad_k(const float* __restrict__ src, u16* __restrict__ dst,
                          int rows, int cols, int rowsPad)
{
    int r = blockIdx.x;
    for (int c = threadIdx.x; c < cols; c += 256)
        dst[(size_t)r * cols + c] = (r < rows) ? f2bf(src[(size_t)r * cols + c]) : (u16)0;
}

// ---------------------------------------------------------------------------
// bf16 MFMA GEMM: out[m][n] = sum_k A[m][k]*B[n][k]  (f32 out)
// ---------------------------------------------------------------------------
__launch_bounds__(256)
__global__ void mfma_gemm_k(const u16* __restrict__ A, const u16* __restrict__ B,
                            float* __restrict__ out, int K, int Nout, int M, int ldo)
{
    __shared__ u16 As[128 * 64];
    __shared__ u16 Bs[128 * 64];
    const int r0 = blockIdx.x * 128, c0 = blockIdx.y * 128;
    const int tid = threadIdx.x;
    const int lane = tid & 63, w = tid >> 6;
    const int wr = (w >> 1) * 64, wc = (w & 1) * 64;
    f32x4 acc[4][4];
#pragma unroll
    for (int m = 0; m < 4; ++m)
#pragma unroll
        for (int n = 0; n < 4; ++n)
            acc[m][n] = (f32x4){0.f, 0.f, 0.f, 0.f};

    const int rlane = lane & 15;
    const int khalf = (lane >> 4) * 16;

    for (int k0 = 0; k0 < K; k0 += 64) {
#pragma unroll
        for (int i = 0; i < 4; ++i) {
            int chunk = i * 256 + tid;
            int row = chunk >> 3, ks = chunk & 7;
            gload16(A + ((size_t)(r0 + row) * K + k0 + ks * 8), (char*)As + chunk * 16);
            gload16(B + ((size_t)(c0 + row) * K + k0 + ks * 8), (char*)Bs + chunk * 16);
        }
        __syncthreads();
#pragma unroll
        for (int ks = 0; ks < 2; ++ks) {
            short8 a[4], b[4];
#pragma unroll
            for (int m = 0; m < 4; ++m)
                a[m] = *(const short8*)((const char*)As + (wr + m * 16 + rlane) * 128 + ks * 64 + khalf);
#pragma unroll
            for (int n = 0; n < 4; ++n)
                b[n] = *(const short8*)((const char*)Bs + (wc + n * 16 + rlane) * 128 + ks * 64 + khalf);
#pragma unroll
            for (int m = 0; m < 4; ++m)
#pragma unroll
                for (int n = 0; n < 4; ++n)
                    acc[m][n] = __builtin_amdgcn_mfma_f32_16x16x32_bf16(a[m], b[n], acc[m][n], 0, 0, 0);
        }
        __syncthreads();
    }
    const int rl = (lane >> 4) * 4, cl = lane & 15;
#pragma unroll
    for (int m = 0; m < 4; ++m) {
#pragma unroll
        for (int n = 0; n < 4; ++n) {
            int col = c0 + wc + n * 16 + cl;
            if (col >= Nout) continue;
#pragma unroll
            for (int r = 0; r < 4; ++r) {
                int row = r0 + wr + m * 16 + rl + r;
                if (row < M) out[(size_t)row * ldo + col] = acc[m][n][r];
            }
        }
    }
}

// ---------------------------------------------------------------------------
// Per-chunk prep: silu(B/C), dt=softplus, acs2 = cumsum(a)*log2e (wave scan).
// ---------------------------------------------------------------------------
__launch_bounds__(256)
__global__ void prep_k(const float* __restrict__ zx, const float* __restrict__ dt_bias,
                       const float* __restrict__ A_log, float* __restrict__ dtb,
                       float* __restrict__ Bb, float* __restrict__ Cb,
                       float* __restrict__ acsb, float* __restrict__ csum)
{
    const int c = blockIdx.x;
    const int l = threadIdx.x;
    const int lane = l & 63, w = l >> 6;
    const int gl = c * 256 + l;
    const bool valid = gl < L_SEQ;
    float v[NH] = {0.f, 0.f, 0.f, 0.f};
    if (valid) {
        const float* row = zx + (size_t)gl * DPROJ;
        float4 bv = *(const float4*)(row + 512);
        float4 cv = *(const float4*)(row + 516);
        float4 dv = *(const float4*)(row + 520);
        float4 bo = make_float4(silu_f(bv.x), silu_f(bv.y), silu_f(bv.z), silu_f(bv.w));
        float4 co = make_float4(silu_f(cv.x), silu_f(cv.y), silu_f(cv.z), silu_f(cv.w));
        *(float4*)(Bb + (size_t)gl * 4) = bo;
        *(float4*)(Cb + (size_t)gl * 4) = co;
        const float* dp = (const float*)&dv;
#pragma unroll
        for (int h = 0; h < NH; ++h) {
            float dt = softplus_f(dp[h] + dt_bias[h]);
            dtb[(size_t)gl * 4 + h] = dt;
            v[h] = -__expf(A_log[h]) * LOG2E * dt;   // log2-scaled a
        }
    }
    // wave-level inclusive scan (64 lanes)
#pragma unroll
    for (int off = 1; off < 64; off <<= 1) {
#pragma unroll
        for (int h = 0; h < NH; ++h) {
            float t = __shfl_up(v[h], off, 64);
            if (lane >= off) v[h] += t;
        }
    }
    __shared__ float wsum[4][NH];
    if (lane == 63)
#pragma unroll
        for (int h = 0; h < NH; ++h) wsum[w][h] = v[h];
    __syncthreads();
#pragma unroll
    for (int h = 0; h < NH; ++h) {
        float o = 0.f;
#pragma unroll
        for (int w2 = 0; w2 < 4; ++w2) if (w2 < w) o += wsum[w2][h];
        v[h] += o;
    }
    if (valid)
#pragma unroll
        for (int h = 0; h < NH; ++h) acsb[(size_t)gl * 4 + h] = v[h];
    if (l == 255)
#pragma unroll
        for (int h = 0; h < NH; ++h) csum[c * 4 + h] = v[h];
}

// ---------------------------------------------------------------------------
// Chunk-end states, partial (acs2/csum2 are log2-scaled).
// ---------------------------------------------------------------------------
__launch_bounds__(256)
__global__ void states_part_k(const float* __restrict__ zx, const float* __restrict__ dtb,
                              const float* __restrict__ Bb, const float* __restrict__ acs,
                              const float* __restrict__ csum, float* __restrict__ spart)
{
    __shared__ float coef[64][16];
    const int c = blockIdx.x, q = blockIdx.y;
    const int tid = threadIdx.x;
    {
        const int l_loc = tid >> 2, h = tid & 3;
        const int gl = c * 256 + q * 64 + l_loc;
        float4 Bv = make_float4(0.f, 0.f, 0.f, 0.f);
        float e = 0.f;
        if (gl < L_SEQ) {
            Bv = *(const float4*)(Bb + (size_t)gl * 4);
            e = exp2f(csum[c * 4 + h] - acs[(size_t)gl * 4 + h]) * dtb[(size_t)gl * 4 + h];
        }
        float4 cf = make_float4(Bv.x * e, Bv.y * e, Bv.z * e, Bv.w * e);
        *(float4*)&coef[l_loc][h * 4] = cf;
    }
    __syncthreads();
    const int h = tid >> 6;
    f32x4 acc = (f32x4){0.f, 0.f, 0.f, 0.f};
#pragma unroll 4
    for (int j = 0; j < 64; ++j) {
        const int gl = c * 256 + q * 64 + j;
        float xv = (gl < L_SEQ) ? zx[(size_t)gl * DPROJ + 256 + tid] : 0.f;
        float xs = silu_f(xv);
        float4 cf = *(const float4*)&coef[j][h * 4];
        acc[0] += cf.x * xs; acc[1] += cf.y * xs;
        acc[2] += cf.z * xs; acc[3] += cf.w * xs;
    }
    *(f32x4*)(spart + ((size_t)(c * 4 + q) * 256 + tid) * 4) = acc;
}

// ---------------------------------------------------------------------------
// Inter-chunk scan with fused q-reduction (csum2 log2-scaled).
// ---------------------------------------------------------------------------
__launch_bounds__(256)
__global__ void chunkscan_k(const float* __restrict__ csum, const float* __restrict__ spart,
                            float* __restrict__ prev)
{
    const int h = blockIdx.x;
    const int tid = threadIdx.x;
    __shared__ float ecs[NCH];
    if (tid < NCH) ecs[tid] = exp2f(csum[tid * 4 + h]);
    __syncthreads();
    float run = 0.f;
#pragma unroll 2
    for (int c = 0; c < NCH; ++c) {
        const float* sp = spart + (size_t)(c * 4) * 1024 + h * 256 + tid;
        float s = sp[0] + sp[1024] + sp[2048] + sp[3072];
        prev[(size_t)c * 1024 + h * 256 + tid] = run;
        run = run * ecs[c] + s;
    }
}

// ---------------------------------------------------------------------------
// MFMA per-chunk output, v2: 8 waves (512 thr), balanced triangular pairing.
// Wave w owns row-frags R0 = w*16 and R1 = 240 - w*16 (9 active (m,ks) each).
// sB holds Bdt = silu(B)*dt (dt folded at stage time); acs2 is log2-scaled.
// ---------------------------------------------------------------------------
__launch_bounds__(512, 4)
__global__ void ychunk_mfma_k(const float* __restrict__ zx, const float* __restrict__ dtb,
                              const float* __restrict__ Bb, const float* __restrict__ Cb,
                              const float* __restrict__ acs, const float* __restrict__ prev,
                              const float* __restrict__ Dv, const int* __restrict__ mor,
                              u16* __restrict__ cat, int catOff)
{
    __shared__ __align__(16) u16 Xt[64 * 256];   // [p][s] bf16, XOR-swizzled
    __shared__ float4 sB[256];                   // Bdt
    __shared__ float4 sC[256];
    __shared__ float  sA2[256];                  // acs * log2e
    __shared__ float4 sPrev[64];

    const int c = blockIdx.x, h = blockIdx.y;
    const int tid = threadIdx.x;
    const int lane = tid & 63, w = tid >> 6;
    const float Dh = Dv[h];

    // ---- stage X^T: wave w covers s in [w*32, w*32+32), p = lane ----
    {
        const int p = lane;
#pragma unroll
        for (int jq = 0; jq < 4; ++jq) {
            const int s0 = w * 32 + jq * 8;
            float xs[8];
#pragma unroll
            for (int j = 0; j < 8; ++j) {
                int gl = c * 256 + s0 + j;
                float xv = (gl < L_SEQ) ? zx[(size_t)gl * DPROJ + 256 + h * HD + p] : 0.f;
                xs[j] = silu_f(xv);
            }
            union { u32 wd[4]; uint4 v4; } pk;
#pragma unroll
            for (int q = 0; q < 4; ++q) pk.wd[q] = cvtpk(xs[2 * q], xs[2 * q + 1]);
            u32 off = (u32)(p * 512 + s0 * 2) ^ (u32)((p & 15) << 4);
            *(uint4*)((char*)Xt + off) = pk.v4;
        }
    }
    // ---- stage Bdt/C/acs2 (tid<256) and prev (tid 256..319) ----
    if (tid < 256) {
        const int s = tid;
        const int gl = c * 256 + s;
        if (gl < L_SEQ) {
            float4 bv = *(const float4*)(Bb + (size_t)gl * 4);
            float dt = dtb[(size_t)gl * 4 + h];
            sB[s] = make_float4(bv.x * dt, bv.y * dt, bv.z * dt, bv.w * dt);
            sC[s] = *(const float4*)(Cb + (size_t)gl * 4);
            sA2[s] = acs[(size_t)gl * 4 + h];
        } else {
            sB[s] = make_float4(0.f, 0.f, 0.f, 0.f);
            sC[s] = make_float4(0.f, 0.f, 0.f, 0.f);
            sA2[s] = 0.f;
        }
    } else if (tid < 320) {
        sPrev[tid - 256] = *(const float4*)(prev + ((size_t)c * 1024 + h * 256 + (tid - 256) * 4));
    }
    __syncthreads();

    const int rl15 = lane & 15, kg = lane >> 4;
    const int R[2] = {w * 16, 240 - w * 16};
    float4 C4[2]; float al2[2]; int lrow[2];
#pragma unroll
    for (int m = 0; m < 2; ++m) {
        lrow[m] = R[m] + rl15;
        C4[m] = sC[lrow[m]];
        al2[m] = sA2[lrow[m]];
    }

    f32x4 acc[2][4];
#pragma unroll
    for (int m = 0; m < 2; ++m)
#pragma unroll
        for (int n = 0; n < 4; ++n)
            acc[m][n] = (f32x4){0.f, 0.f, 0.f, 0.f};

    for (int ks = 0; ks < 8; ++ks) {
        if (ks * 32 > R[1] + 15) continue;       // wave-uniform: deepest frag done
        const int s0 = ks * 32 + kg * 8;
        short8 bf[4];
#pragma unroll
        for (int n = 0; n < 4; ++n) {
            int col = n * 16 + rl15;
            u32 off = (u32)(col * 512 + ks * 64 + kg * 16) ^ (u32)((col & 15) << 4);
            bf[n] = *(const short8*)((const char*)Xt + off);
        }
        float4 Bsv[8]; float a2[8];
#pragma unroll
        for (int j = 0; j < 8; ++j) { Bsv[j] = sB[s0 + j]; a2[j] = sA2[s0 + j]; }
#pragma unroll
        for (int m = 0; m < 2; ++m) {
            if (ks * 32 <= R[m] + 15) {
                float vv[8];
#pragma unroll
                for (int j = 0; j < 8; ++j) {
                    int s = s0 + j;
                    float dot = C4[m].x * Bsv[j].x + C4[m].y * Bsv[j].y
                              + C4[m].z * Bsv[j].z + C4[m].w * Bsv[j].w;
                    float v = dot * exp2f(al2[m] - a2[j]);
                    v = (s <= lrow[m]) ? v : 0.f;
                    v = (s == lrow[m]) ? v + Dh : v;
                    vv[j] = v;
                }
                union { u32 wd[4]; short8 v; } aw;
#pragma unroll
                for (int q = 0; q < 4; ++q) aw.wd[q] = cvtpk(vv[2 * q], vv[2 * q + 1]);
#pragma unroll
                for (int n = 0; n < 4; ++n)
                    acc[m][n] = __builtin_amdgcn_mfma_f32_16x16x32_bf16(aw.v, bf[n], acc[m][n], 0, 0, 0);
            }
        }
    }

    // ---- epilogue: prev contribution, gating, scatter ----
#pragma unroll
    for (int m = 0; m < 2; ++m) {
#pragma unroll
        for (int r = 0; r < 4; ++r) {
            const int row = R[m] + kg * 4 + r;
            const int gl = c * 256 + row;
            const bool valid = gl < L_SEQ;
            const float4 Cr = sC[row];
            const float ea = exp2f(sA2[row]);
            const int pos = valid ? mor[gl] : 0;
            const float* zrow = zx + (size_t)gl * DPROJ + h * HD;
            u16* orow = cat + (size_t)pos * 512 + catOff + h * HD;
#pragma unroll
            for (int n = 0; n < 4; ++n) {
                const int col = n * 16 + rl15;
                float4 pv = sPrev[col];
                float y = acc[m][n][r]
                        + ea * (Cr.x * pv.x + Cr.y * pv.y + Cr.z * pv.z + Cr.w * pv.w);
                if (valid) {
                    float z = zrow[col];
                    orow[col] = f2bf(y * silu_f(z));
                }
            }
        }
    }
}

// ---------------------------------------------------------------------------
// LayerNorm over channel dim (256).
// ---------------------------------------------------------------------------
__launch_bounds__(256)
__global__ void ln_k(const float* __restrict__ pin, const float* __restrict__ g,
                     const float* __restrict__ b, float* __restrict__ pout)
{
    const int l = blockIdx.x, c = threadIdx.x;
    float v = pin[(size_t)l * 256 + c];
    float s = v, s2 = v * v;
#pragma unroll
    for (int o = 32; o > 0; o >>= 1) { s += __shfl_down(s, o); s2 += __shfl_down(s2, o); }
    __shared__ float ws0[4], ws1[4];
    if ((c & 63) == 0) { ws0[c >> 6] = s; ws1[c >> 6] = s2; }
    __syncthreads();
    float ts = ws0[0] + ws0[1] + ws0[2] + ws0[3];
    float t2 = ws1[0] + ws1[1] + ws1[2] + ws1[3];
    float mu = ts * (1.f / 256.f);
    float var = t2 * (1.f / 256.f) - mu * mu;
    float r = rsqrtf(var + 1e-6f);
    pout[(size_t)l * 256 + c] = (v - mu) * r * g[c] + b[c];
}

// ---------------------------------------------------------------------------
// Transpose (L x 256) -> (256 x L).
// ---------------------------------------------------------------------------
__global__ void transpose_k(const float* __restrict__ pin, float* __restrict__ pout)
{
    __shared__ float t[64][65];
    const int l0 = blockIdx.x * 64, c0 = blockIdx.y * 64;
    const int tx = threadIdx.x, ty = threadIdx.y;
#pragma unroll
    for (int j = 0; j < 16; ++j) {
        int row = ty + j * 4;
        int l = l0 + row;
        t[row][tx] = (l < L_SEQ) ? pin[(size_t)l * 256 + c0 + tx] : 0.f;
    }
    __syncthreads();
#pragma unroll
    for (int j = 0; j < 16; ++j) {
        int crow = ty + j * 4;
        int lcol = l0 + tx;
        if (lcol < L_SEQ) pout[(size_t)(c0 + crow) * L_SEQ + lcol] = t[tx][crow];
    }
}

// ---------------------------------------------------------------------------
extern "C" void kernel_launch(void* const* d_in, const int* in_sizes, int n_in,
                              void* d_out, int out_size, void* d_ws, size_t ws_size,
                              hipStream_t stream)
{
    const float* x        = (const float*)d_in[0];
    const float* W_in[2]  = {(const float*)d_in[1], (const float*)d_in[2]};
    const float* dt_b[2]  = {(const float*)d_in[3], (const float*)d_in[4]};
    const float* A_log[2] = {(const float*)d_in[5], (const float*)d_in[6]};
    const float* Dv[2]    = {(const float*)d_in[7], (const float*)d_in[8]};
    const float* W_out    = (const float*)d_in[9];
    const float* ln_g     = (const float*)d_in[10];
    const float* ln_b     = (const float*)d_in[11];
    const int*   mor[2]   = {(const int*)d_in[12], (const int*)d_in[13]};
    const int*   inv[2]   = {(const int*)d_in[14], (const int*)d_in[15]};

    char* ws = (char*)d_ws;
    size_t off = 0;
    auto alloc = [&](size_t bytes) { char* p = ws + off; off += (bytes + 255) & ~(size_t)255; return p; };
    float* zx    = (float*)alloc((size_t)L_SEQ * DPROJ * 4);   // reused as proj out
    u16*   cat   = (u16*)  alloc((size_t)MPAD * 512 * 2);      // bf16; reused (f32) as LN out
    u16*   xg    = (u16*)  alloc((size_t)MPAD * 256 * 2);
    u16*   wbuf  = (u16*)  alloc((size_t)640 * 256 * 2);
    float* dtb   = (float*)alloc((size_t)L_SEQ * 4 * 4);
    float* Bb    = (float*)alloc((size_t)L_SEQ * 4 * 4);
    float* Cb    = (float*)alloc((size_t)L_SEQ * 4 * 4);
    float* acsb  = (float*)alloc((size_t)L_SEQ * 4 * 4);
    float* csum  = (float*)alloc((size_t)NCH * 4 * 4);
    float* spart = (float*)alloc((size_t)NCH * 4 * 1024 * 4);
    float* prev  = (float*)alloc((size_t)NCH * 1024 * 4);
    float* proj  = zx;           // zx dead after both paths
    float* lnout = (float*)cat;  // cat dead after out-proj

    for (int path = 0; path < 2; ++path) {
        convpad_k<<<640, 256, 0, stream>>>(W_in[path], wbuf, 524, 256, 640);
        gather_k<<<507, 256, 0, stream>>>(x, inv[path], xg);
        zero_k<<<(112 * 256 + 255) / 256, 256, 0, stream>>>(xg + (size_t)L_SEQ * 256, 112 * 256);
        mfma_gemm_k<<<dim3(254, 5), 256, 0, stream>>>(xg, wbuf, zx, 256, 524, L_SEQ, DPROJ);
        prep_k<<<NCH, 256, 0, stream>>>(zx, dt_b[path], A_log[path], dtb, Bb, Cb, acsb, csum);
        states_part_k<<<dim3(NCH, 4), 256, 0, stream>>>(zx, dtb, Bb, acsb, csum, spart);
        chunkscan_k<<<4, 256, 0, stream>>>(csum, spart, prev);
        ychunk_mfma_k<<<dim3(NCH, NH), 512, 0, stream>>>(zx, dtb, Bb, Cb, acsb, prev,
                                                         Dv[path], mor[path], cat, path * 256);
    }
    zero_k<<<(112 * 512 + 255) / 256, 256, 0, stream>>>(cat + (size_t)L_SEQ * 512, 112 * 512);
    convpad_k<<<256, 256, 0, stream>>>(W_out, wbuf, 256, 512, 256);
    mfma_gemm_k<<<dim3(254, 2), 256, 0, stream>>>(cat, wbuf, proj, 512, 256, L_SEQ, 256);
    ln_k<<<L_SEQ, 256, 0, stream>>>(proj, ln_g, ln_b, lnout);
    transpose_k<<<dim3(507, 4), dim3(64, 4), 0, stream>>>(lnout, (float*)d_out);
}